// Round 8
// baseline (421.195 us; speedup 1.0000x reference)
//
#include <hip/hip_runtime.h>
#include <math.h>

// ---------------------------------------------------------------------------
// GAT 2-layer pipeline for MI355X.
// N=50000 nodes, E=850000 edges (incl self loops), feat 256, H=4 x 64 -> 256.
//
//   convert_w2 / convert_h8: fp32 -> fp16 (one dispatch for both W's).
//   CSR build: zero, hist, scan1, scan23 (merged scan2+scan3), scatter,
//     sort_csr (canonical ascending-src order per segment).
//   gemm_mfma: C[fp16] = A[fp16] @ B[fp16]^T single-pass 16x16x32_f16 MFMA
//     (r7: absmax unchanged vs split-bf16 — fp16-storage error dominates).
//   scompute: wave-per-node, ushort4-vectorized.
//   aggregate4: wave-per-node fused softmax-stats + gather-aggregate.
//     Determinism: scatter's atomicAdd permutes segments per call; sort_csr
//     canonicalizes -> bitwise-identical output every call (tripwire).
//     r4 lesson: do NOT widen per-edge footprint (acc32/96-shuffle regressed).
//     r6 lesson: rotating (s,p) prefetch regressed — compiler scheduling wins.
//     r8: gather unrolled x2 at CONSTANT footprint — same acc[16], same
//     epilogue; 4 independent 16B loads issued per iteration (MLP 2->4).
//     FMA order per lane unchanged -> bitwise identical to r7.
// ---------------------------------------------------------------------------

typedef __attribute__((ext_vector_type(8))) short short8;
typedef __attribute__((ext_vector_type(8))) unsigned short ushort8;
typedef __attribute__((ext_vector_type(4))) float f32x4;           // MFMA acc
typedef _Float16 half8 __attribute__((ext_vector_type(8)));        // 8 x fp16

__device__ inline unsigned short f2h(float f) {
    _Float16 h = (_Float16)f;
    unsigned short u;
    __builtin_memcpy(&u, &h, 2);
    return u;
}
__device__ inline float h2f(unsigned short u) {
    _Float16 h;
    __builtin_memcpy(&h, &u, 2);
    return (float)h;
}

// fp32 -> fp16, 8 elems/thread
__global__ void convert_h8(const float* __restrict__ X, unsigned short* __restrict__ Xh,
                           long n) {
    long i = ((long)blockIdx.x * 256 + threadIdx.x) * 8;
    if (i + 8 <= n) {
        float4 v0 = *(const float4*)&X[i];
        float4 v1 = *(const float4*)&X[i + 4];
        ushort8 o;
        o[0] = f2h(v0.x); o[1] = f2h(v0.y); o[2] = f2h(v0.z); o[3] = f2h(v0.w);
        o[4] = f2h(v1.x); o[5] = f2h(v1.y); o[6] = f2h(v1.z); o[7] = f2h(v1.w);
        *(ushort8*)&Xh[i] = o;
    } else {
        for (long k = i; k < n; ++k) Xh[k] = f2h(X[k]);
    }
}

// both 65536-elem weight matrices in one dispatch: blocks 0..31 -> W1, 32..63 -> W2
__global__ void convert_w2(const float* __restrict__ WA, const float* __restrict__ WB,
                           unsigned short* __restrict__ DA, unsigned short* __restrict__ DB) {
    const bool second = blockIdx.x >= 32;
    const float* S = second ? WB : WA;
    unsigned short* D = second ? DB : DA;
    long i = ((long)(blockIdx.x & 31) * 256 + threadIdx.x) * 8;   // exact fit 65536
    float4 v0 = *(const float4*)&S[i];
    float4 v1 = *(const float4*)&S[i + 4];
    ushort8 o;
    o[0] = f2h(v0.x); o[1] = f2h(v0.y); o[2] = f2h(v0.z); o[3] = f2h(v0.w);
    o[4] = f2h(v1.x); o[5] = f2h(v1.y); o[6] = f2h(v1.z); o[7] = f2h(v1.w);
    *(ushort8*)&D[i] = o;
}

// C[M x 256] (fp16) = A[M x 256] (fp16) @ B^T (fp16), single-pass f16 MFMA.
// 128x128 tile, BK=32, 4 waves; each wave: 2 m-frags x 8 n-frags.
// Pad-40 LDS rows: b128 reads are 2-way bank aliased = free.
__global__ __launch_bounds__(256) void gemm_mfma(const unsigned short* __restrict__ A_g,
                                                 const unsigned short* __restrict__ B_g,
                                                 unsigned short* __restrict__ C, int M) {
    __shared__ unsigned short Ah[128 * 40];
    __shared__ unsigned short Bh[128 * 40];
    const int tid = threadIdx.x;
    const int m0 = blockIdx.x * 128;
    const int n0 = blockIdx.y * 128;
    const int w = tid >> 6, lane = tid & 63;
    const int l15 = lane & 15, q = lane >> 4;

    f32x4 acc[2][8];
    #pragma unroll
    for (int mt = 0; mt < 2; ++mt)
        #pragma unroll
        for (int nt = 0; nt < 8; ++nt) acc[mt][nt] = (f32x4){0.f, 0.f, 0.f, 0.f};

    const int ar = tid >> 1;          // 0..127 (row within tile)
    const int ak = (tid & 1) * 16;    // 0 or 16 (k-offset, 16 elems)

    for (int k0 = 0; k0 < 256; k0 += 32) {
        int gm = m0 + ar;
        if (gm < M) {
            const unsigned short* a0 = &A_g[(size_t)gm * 256 + k0 + ak];
            *(ushort8*)&Ah[ar * 40 + ak]     = *(const ushort8*)a0;
            *(ushort8*)&Ah[ar * 40 + ak + 8] = *(const ushort8*)(a0 + 8);
        } else {
            ushort8 z = (ushort8){0, 0, 0, 0, 0, 0, 0, 0};
            *(ushort8*)&Ah[ar * 40 + ak]     = z;
            *(ushort8*)&Ah[ar * 40 + ak + 8] = z;
        }
        {
            const unsigned short* b0 = &B_g[(size_t)(n0 + ar) * 256 + k0 + ak];
            *(ushort8*)&Bh[ar * 40 + ak]     = *(const ushort8*)b0;
            *(ushort8*)&Bh[ar * 40 + ak + 8] = *(const ushort8*)(b0 + 8);
        }
        __syncthreads();
        half8 a[2];
        #pragma unroll
        for (int mt = 0; mt < 2; ++mt) {
            int rowA = w * 32 + mt * 16 + l15;
            a[mt] = *(half8*)&Ah[rowA * 40 + q * 8];
        }
        #pragma unroll
        for (int nt = 0; nt < 8; ++nt) {
            int rowB = nt * 16 + l15;
            half8 bf = *(half8*)&Bh[rowB * 40 + q * 8];
            #pragma unroll
            for (int mt = 0; mt < 2; ++mt)
                acc[mt][nt] = __builtin_amdgcn_mfma_f32_16x16x32_f16(a[mt], bf, acc[mt][nt], 0, 0, 0);
        }
        __syncthreads();
    }
    #pragma unroll
    for (int mt = 0; mt < 2; ++mt) {
        #pragma unroll
        for (int nt = 0; nt < 8; ++nt) {
            #pragma unroll
            for (int r = 0; r < 4; ++r) {
                int gm = m0 + w * 32 + mt * 16 + q * 4 + r;
                if (gm < M) C[(size_t)gm * 256 + n0 + nt * 16 + l15] = f2h(acc[mt][nt][r]);
            }
        }
    }
}

// -------------------- CSR build --------------------
__global__ void zero_int(int* __restrict__ p, int n) {
    int i = blockIdx.x * 256 + threadIdx.x;
    if (i < n) p[i] = 0;
}

__global__ void hist_kernel(const int* __restrict__ dst, int* __restrict__ deg, int E) {
    int i = blockIdx.x * 256 + threadIdx.x;
    if (i < E) atomicAdd(&deg[dst[i]], 1);
}

__global__ __launch_bounds__(1024) void scan1(const int* __restrict__ deg,
                                              int* __restrict__ lex,
                                              int* __restrict__ bsums, int n) {
    __shared__ int sh[1024];
    int tid = threadIdx.x;
    int i = blockIdx.x * 1024 + tid;
    int v = (i < n) ? deg[i] : 0;
    sh[tid] = v;
    __syncthreads();
    #pragma unroll
    for (int off = 1; off < 1024; off <<= 1) {
        int t2 = (tid >= off) ? sh[tid - off] : 0;
        __syncthreads();
        sh[tid] += t2;
        __syncthreads();
    }
    if (i < n) lex[i] = sh[tid] - v;
    if (tid == 1023) bsums[blockIdx.x] = sh[1023];
}

// merged scan2+scan3: first wave scans the <=64 block sums, then the block
// applies its exclusive offset. Block 0 also writes offs[n] = grand total.
__global__ __launch_bounds__(1024) void scan23(int* __restrict__ offs,
                                               int* __restrict__ cur,
                                               const int* __restrict__ bsums,
                                               int n, int nb) {
    __shared__ int s_boff, s_total;
    int tid = threadIdx.x;
    if (tid < 64) {
        int bv = (tid < nb) ? bsums[tid] : 0;
        int v = bv;
        #pragma unroll
        for (int off = 1; off < 64; off <<= 1) {
            int t = __shfl_up(v, off, 64);
            if (tid >= off) v += t;
        }
        int incl_bid = __shfl(v, blockIdx.x, 64);
        int bv_bid   = __shfl(bv, blockIdx.x, 64);
        int total    = __shfl(v, nb - 1, 64);
        if (tid == 0) {
            s_boff = incl_bid - bv_bid;   // exclusive prefix for this block
            s_total = total;
        }
    }
    __syncthreads();
    int i = blockIdx.x * 1024 + tid;
    if (i < n) {
        int o = offs[i] + s_boff;
        offs[i] = o;
        cur[i] = o;
    }
    if (blockIdx.x == 0 && tid == 0) offs[n] = s_total;
}

__global__ void scatter_kernel(const int* __restrict__ src, const int* __restrict__ dst,
                               int* __restrict__ cur, int* __restrict__ sorted, int E) {
    int i = blockIdx.x * 256 + threadIdx.x;
    if (i < E) {
        int p = atomicAdd(&cur[dst[i]], 1);
        sorted[p] = src[i];
    }
}

// Canonicalize each CSR segment (deg<=64) with a 64-lane bitonic sort.
// deg>64 segments are left as-is (aggregate4's big path is order-invariant).
// No barriers -> per-wave early return is safe.
__global__ __launch_bounds__(256) void sort_csr(const int* __restrict__ offs,
                                                int* __restrict__ sorted, int N) {
    const int w = threadIdx.x >> 6, lane = threadIdx.x & 63;
    const int node = blockIdx.x * 4 + w;
    if (node >= N) return;
    const int b = offs[node], e = offs[node + 1];
    const int deg = e - b;
    if (deg < 2 || deg > 64) return;
    int key = (lane < deg) ? sorted[b + lane] : 0x7FFFFFFF;
    #pragma unroll
    for (int k = 2; k <= 64; k <<= 1) {
        #pragma unroll
        for (int j = k >> 1; j > 0; j >>= 1) {
            int other = __shfl_xor(key, j, 64);
            bool keepMin = ((lane & j) == 0) == ((lane & k) == 0);
            int mn = min(key, other), mh = max(key, other);
            key = keepMin ? mn : mh;
        }
    }
    if (lane < deg) sorted[b + lane] = key;
}

// -------------------- attention scalars (fp16 hp in) --------------------
// Wave per node, 4 nodes/block. Lane covers 4 contiguous features (8B
// ushort4 load). Fixed-order butterflies -> deterministic.
template <int NH>
__global__ __launch_bounds__(256) void scompute(const unsigned short* __restrict__ hp,
                                                const float* __restrict__ a_src,
                                                const float* __restrict__ a_dst,
                                                float* __restrict__ s_src,
                                                float* __restrict__ s_dst, int N) {
    const int w = threadIdx.x >> 6, lane = threadIdx.x & 63;
    const int node = blockIdx.x * 4 + w;
    if (node >= N) return;          // no barriers below — safe
    const int f0 = lane * 4;
    ushort4 uv = *(const ushort4*)(hp + (size_t)node * 256 + f0);
    float4 as = *(const float4*)(a_src + f0);
    float4 ad = *(const float4*)(a_dst + f0);
    float x0 = h2f(uv.x), x1 = h2f(uv.y), x2 = h2f(uv.z), x3 = h2f(uv.w);
    float p1 = x0 * as.x + x1 * as.y + x2 * as.z + x3 * as.w;
    float p2 = x0 * ad.x + x1 * ad.y + x2 * ad.z + x3 * ad.w;
    if constexpr (NH == 4) {
        #pragma unroll
        for (int off = 1; off < 16; off <<= 1) {
            p1 += __shfl_xor(p1, off, 64);
            p2 += __shfl_xor(p2, off, 64);
        }
        if ((lane & 15) == 0) {
            s_src[node * 4 + (lane >> 4)] = p1;
            s_dst[node * 4 + (lane >> 4)] = p2;
        }
    } else {
        #pragma unroll
        for (int off = 1; off < 64; off <<= 1) {
            p1 += __shfl_xor(p1, off, 64);
            p2 += __shfl_xor(p2, off, 64);
        }
        if (lane == 0) {
            s_src[node] = p1;
            s_dst[node] = p2;
        }
    }
}

// -------------------- fused stats + aggregation (bitwise-deterministic) ----
// One wave per node, 4 nodes per block. CSR segments are pre-sorted
// (sort_csr) so order is canonical. Stats phase computes pv per edge,
// stores (src, pv[]) to LDS. One barrier. Gather: 4 edges/iter x unroll 2
// (8 edges per unrolled iteration, constant acc[16] footprint).
// F16OUT=true: write output as fp16 (A-operand of the next GEMM).
template <int NH, bool RELU, bool F16OUT>
__global__ __launch_bounds__(256) void aggregate4(const unsigned short* __restrict__ hp,
                                                  const float* __restrict__ ssrc,
                                                  const float* __restrict__ sdst,
                                                  const int* __restrict__ offs,
                                                  const int* __restrict__ sorted,
                                                  float* __restrict__ out,
                                                  unsigned short* __restrict__ outh, int N) {
    __shared__ int   s_sh[4][64];
    __shared__ float p_sh[4][64][NH];

    const int w = threadIdx.x >> 6, lane = threadIdx.x & 63;
    const int node_raw = blockIdx.x * 4 + w;
    const bool node_ok = node_raw < N;
    const int node = node_ok ? node_raw : (N - 1);   // clamp; no early return
    constexpr int NF = 256 / NH;

    const int b = offs[node], e = offs[node + 1];
    const int deg = e - b;

    float sv[NH];
    #pragma unroll
    for (int h = 0; h < NH; ++h) sv[h] = sdst[node * NH + h];

    float lv[NH], mx[NH];
    const bool small = (deg <= 64);

    if (small) {
        const bool valid = lane < deg;
        const int mys = valid ? sorted[b + lane] : 0;   // pre-sorted ascending

        // ---- stats on sorted sequence ----
        float evv[NH];
        if constexpr (NH == 4) {
            float4 sa = *(const float4*)&ssrc[(size_t)mys * 4];
            evv[0] = sa.x + sv[0]; evv[1] = sa.y + sv[1];
            evv[2] = sa.z + sv[2]; evv[3] = sa.w + sv[3];
        } else {
            evv[0] = ssrc[mys] + sv[0];
        }
        #pragma unroll
        for (int h = 0; h < NH; ++h) {
            float ev = evv[h];
            ev = ev > 0.f ? ev : 0.2f * ev;
            evv[h] = valid ? ev : -INFINITY;
            mx[h] = evv[h];
        }
        #pragma unroll
        for (int off = 32; off > 0; off >>= 1)
            #pragma unroll
            for (int h = 0; h < NH; ++h)
                mx[h] = fmaxf(mx[h], __shfl_xor(mx[h], off, 64));

        float pv[NH];
        #pragma unroll
        for (int h = 0; h < NH; ++h) {
            pv[h] = valid ? __expf(evv[h] - mx[h]) : 0.f;
            lv[h] = pv[h];
        }
        #pragma unroll
        for (int off = 32; off > 0; off >>= 1)
            #pragma unroll
            for (int h = 0; h < NH; ++h)
                lv[h] += __shfl_xor(lv[h], off, 64);

        // stash sorted (src, pv[]) for the gather phase
        s_sh[w][lane] = mys;
        #pragma unroll
        for (int h = 0; h < NH; ++h) p_sh[w][lane][h] = pv[h];
    } else {
        // ---- deg > 64 (never populated for this graph; kept correct) ----
        #pragma unroll
        for (int h = 0; h < NH; ++h) mx[h] = -INFINITY;
        for (int c = b + lane; c < e; c += 64) {
            int s = sorted[c];
            #pragma unroll
            for (int h = 0; h < NH; ++h) {
                float ev = ssrc[s * NH + h] + sv[h];
                ev = ev > 0.f ? ev : 0.2f * ev;
                mx[h] = fmaxf(mx[h], ev);   // max is order-invariant
            }
        }
        #pragma unroll
        for (int off = 32; off > 0; off >>= 1)
            #pragma unroll
            for (int h = 0; h < NH; ++h)
                mx[h] = fmaxf(mx[h], __shfl_xor(mx[h], off, 64));
    }

    __syncthreads();   // all waves reach this exactly once

    if (small) {
        // ---- gather: 4 edges/iter, unrolled x2 (constant footprint) ----
        const int quarter = lane >> 4;
        const int l16 = lane & 15;
        const int f0 = l16 * 16;
        const int head = f0 / NF;        // NH=4: l16/4; NH=1: 0

        float acc[16];
        #pragma unroll
        for (int k = 0; k < 16; ++k) acc[k] = 0.f;

        const int iters = (deg + 3) >> 2;
        int t2 = 0;
        for (; t2 + 2 <= iters; t2 += 2) {
            int j0 = 4 * t2 + quarter;
            int j1 = j0 + 4;
            bool ok0 = j0 < deg, ok1 = j1 < deg;
            int jj0 = ok0 ? j0 : 0, jj1 = ok1 ? j1 : 0;
            int s0 = s_sh[w][jj0];
            int s1 = s_sh[w][jj1];
            float p0 = ok0 ? p_sh[w][jj0][head] : 0.f;
            float p1 = ok1 ? p_sh[w][jj1][head] : 0.f;
            const unsigned short* r0 = hp + (size_t)s0 * 256 + f0;
            const unsigned short* r1 = hp + (size_t)s1 * 256 + f0;
            half8 va0 = *(const half8*)(r0);
            half8 va1 = *(const half8*)(r0 + 8);
            half8 vb0 = *(const half8*)(r1);
            half8 vb1 = *(const half8*)(r1 + 8);
            #pragma unroll
            for (int k = 0; k < 8; ++k) {
                acc[k]     = fmaf(p0, (float)va0[k], acc[k]);
                acc[8 + k] = fmaf(p0, (float)va1[k], acc[8 + k]);
            }
            #pragma unroll
            for (int k = 0; k < 8; ++k) {
                acc[k]     = fmaf(p1, (float)vb0[k], acc[k]);
                acc[8 + k] = fmaf(p1, (float)vb1[k], acc[8 + k]);
            }
        }
        if (t2 < iters) {
            int j = 4 * t2 + quarter;
            bool jv = j < deg;
            int jj = jv ? j : 0;
            int s = s_sh[w][jj];
            float p = jv ? p_sh[w][jj][head] : 0.f;
            const unsigned short* row = hp + (size_t)s * 256 + f0;
            half8 v0 = *(const half8*)(row);
            half8 v1 = *(const half8*)(row + 8);
            #pragma unroll
            for (int k = 0; k < 8; ++k) {
                acc[k]     = fmaf(p, (float)v0[k], acc[k]);
                acc[8 + k] = fmaf(p, (float)v1[k], acc[8 + k]);
            }
        }
        // reduce across the 4 edge-quarters (wave-uniform, all lanes active)
        #pragma unroll
        for (int k = 0; k < 16; ++k) {
            acc[k] += __shfl_xor(acc[k], 16, 64);
            acc[k] += __shfl_xor(acc[k], 32, 64);
        }
        if (node_ok && lane < 16) {
            float li = 1.0f / (lv[head] + 1e-16f);
            float o[16];
            #pragma unroll
            for (int k = 0; k < 16; ++k) {
                o[k] = acc[k] * li;
                if (RELU) o[k] = fmaxf(o[k], 0.f);
            }
            if constexpr (F16OUT) {
                ushort8 u0, u1;
                #pragma unroll
                for (int k = 0; k < 8; ++k) {
                    u0[k] = f2h(o[k]);
                    u1[k] = f2h(o[8 + k]);
                }
                *(ushort8*)&outh[(size_t)node * 256 + f0]     = u0;
                *(ushort8*)&outh[(size_t)node * 256 + f0 + 8] = u1;
            } else {
                float* op = &out[(size_t)node * 256 + f0];
                *(float4*)&op[0]  = make_float4(o[0], o[1], o[2], o[3]);
                *(float4*)&op[4]  = make_float4(o[4], o[5], o[6], o[7]);
                *(float4*)&op[8]  = make_float4(o[8], o[9], o[10], o[11]);
                *(float4*)&op[12] = make_float4(o[12], o[13], o[14], o[15]);
            }
        }
    } else {
        // ---- deg > 64 deterministic ascending-src sweep (rare path) ----
        const int half = lane >> 5;
        const int l32 = lane & 31;
        const int f0 = l32 * 8;
        const int head = f0 / NF;

        float acc[8];
        #pragma unroll
        for (int k = 0; k < 8; ++k) acc[k] = 0.f;
        #pragma unroll
        for (int h = 0; h < NH; ++h) lv[h] = 0.f;

        int last = -1, round = 0;
        for (;;) {
            int myMin = 0x7FFFFFFF, myCnt = 0;
            for (int c = b + lane; c < e; c += 64) {
                int s = sorted[c];
                if (s > last) {
                    if (s < myMin) { myMin = s; myCnt = 1; }
                    else if (s == myMin) ++myCnt;
                }
            }
            #pragma unroll
            for (int off = 32; off > 0; off >>= 1) {
                int om = __shfl_xor(myMin, off, 64);
                int oc = __shfl_xor(myCnt, off, 64);
                if (om < myMin) { myMin = om; myCnt = oc; }
                else if (om == myMin) myCnt += oc;
            }
            if (myMin == 0x7FFFFFFF) break;     // wave-uniform exit
            const bool mine = ((round & 1) == half);
            float cf = (float)myCnt;
            float ph[NH];
            #pragma unroll
            for (int h = 0; h < NH; ++h) {
                float ev = ssrc[myMin * NH + h] + sv[h];
                ev = ev > 0.f ? ev : 0.2f * ev;
                ph[h] = __expf(ev - mx[h]);
            }
            if (mine && l32 == 0) {             // one lane per half owns lv
                #pragma unroll
                for (int h = 0; h < NH; ++h) lv[h] += cf * ph[h];
            }
            if (mine) {
                float p = cf * ph[head];
                half8 v = *(const half8*)(hp + (size_t)myMin * 256 + f0);
                #pragma unroll
                for (int k = 0; k < 8; ++k) acc[k] = fmaf(p, (float)v[k], acc[k]);
            }
            last = myMin; ++round;
        }
        #pragma unroll
        for (int off = 32; off > 0; off >>= 1)
            #pragma unroll
            for (int h = 0; h < NH; ++h)
                lv[h] += __shfl_xor(lv[h], off, 64);

        #pragma unroll
        for (int k = 0; k < 8; ++k) acc[k] += __shfl_xor(acc[k], 32, 64);

        if (node_ok && lane < 32) {
            float li = 1.0f / (lv[head] + 1e-16f);
            float o[8];
            #pragma unroll
            for (int k = 0; k < 8; ++k) {
                o[k] = acc[k] * li;
                if (RELU) o[k] = fmaxf(o[k], 0.f);
            }
            if constexpr (F16OUT) {
                ushort8 u0;
                #pragma unroll
                for (int k = 0; k < 8; ++k) u0[k] = f2h(o[k]);
                *(ushort8*)&outh[(size_t)node * 256 + f0] = u0;
            } else {
                *(float4*)&out[(size_t)node * 256 + f0]     = make_float4(o[0], o[1], o[2], o[3]);
                *(float4*)&out[(size_t)node * 256 + f0 + 4] = make_float4(o[4], o[5], o[6], o[7]);
            }
        }
    }
}

// ---------------------------------------------------------------------------
extern "C" void kernel_launch(void* const* d_in, const int* in_sizes, int n_in,
                              void* d_out, int out_size, void* d_ws, size_t ws_size,
                              hipStream_t stream) {
    const float* x   = (const float*)d_in[0];
    const int*   ei  = (const int*)d_in[1];
    const float* W1  = (const float*)d_in[2];
    const float* a1s = (const float*)d_in[3];
    const float* a1d = (const float*)d_in[4];
    const float* W2  = (const float*)d_in[5];
    const float* a2s = (const float*)d_in[6];
    const float* a2d = (const float*)d_in[7];
    float* out = (float*)d_out;

    const int N = in_sizes[0] / 256;
    const int E = in_sizes[1] / 2;
    const int* src = ei;
    const int* dst = ei + E;

    // workspace carve-up
    unsigned short* hp = (unsigned short*)d_ws;     // N*256 fp16
    float* ssrc  = (float*)(hp + (size_t)N * 256);  // N*4
    float* sdst  = ssrc + (size_t)N * 4;            // N*4
    int*   deg   = (int*)(sdst + (size_t)N * 4);    // N
    int*   cur   = deg + N;                         // N
    int*   offs  = cur + N;                         // N+1
    int*   sorted= offs + N + 1;                    // E
    int*   bsums = sorted + E;                      // 64
    int*   boffs = bsums + 64;                      // 64 (unused, kept for layout)
    unsigned short* w1h = (unsigned short*)(boffs + 64);  // 65536 fp16
    unsigned short* w2h = w1h + 65536;                    // 65536 fp16

    // d_out doubles as fp16 scratch: xh (layer-1 A) in the first half,
    // hh (layer-1 output = layer-2 A) in the second half. Both dead before
    // the final aggregate overwrites d_out with fp32 output.
    unsigned short* xh = (unsigned short*)d_out;    // N*256 fp16
    unsigned short* hh = xh + (size_t)N * 256;      // N*256 fp16

    const int nb = (N + 1023) / 1024;

    // ---- weight + input fp16 conversion ----
    convert_w2<<<64, 256, 0, stream>>>(W1, W2, w1h, w2h);
    long nx = (long)N * 256;
    convert_h8<<<(int)((nx / 8 + 255) / 256), 256, 0, stream>>>(x, xh, nx);

    // ---- CSR build ----
    zero_int<<<(N + 255) / 256, 256, 0, stream>>>(deg, N);
    hist_kernel<<<(E + 255) / 256, 256, 0, stream>>>(dst, deg, E);
    scan1<<<nb, 1024, 0, stream>>>(deg, offs, bsums, N);
    scan23<<<nb, 1024, 0, stream>>>(offs, cur, bsums, N, nb);
    scatter_kernel<<<(E + 255) / 256, 256, 0, stream>>>(src, dst, cur, sorted, E);

    dim3 gg((N + 127) / 128, 2);
    int aggblocks = (N + 3) / 4;
    sort_csr<<<aggblocks, 256, 0, stream>>>(offs, sorted, N);

    // ---- layer 1 ----
    gemm_mfma<<<gg, 256, 0, stream>>>(xh, w1h, hp, N);
    scompute<4><<<aggblocks, 256, 0, stream>>>(hp, a1s, a1d, ssrc, sdst, N);
    aggregate4<4, true, true><<<aggblocks, 256, 0, stream>>>(hp, ssrc, sdst, offs, sorted,
                                                             nullptr, hh, N);

    // ---- layer 2 ----
    gemm_mfma<<<gg, 256, 0, stream>>>(hh, w2h, hp, N);
    scompute<1><<<aggblocks, 256, 0, stream>>>(hp, a2s, a2d, ssrc, sdst, N);
    aggregate4<1, false, false><<<aggblocks, 256, 0, stream>>>(hp, ssrc, sdst, offs, sorted,
                                                               out, nullptr, N);
}

// Round 9
// 415.073 us; speedup vs baseline: 1.0148x; 1.0148x over previous
//
#include <hip/hip_runtime.h>
#include <math.h>

// ---------------------------------------------------------------------------
// GAT 2-layer pipeline for MI355X.
// N=50000 nodes, E=850000 edges (incl self loops), feat 256, H=4 x 64 -> 256.
//
//   convert_w2: both W's fp32 -> fp16 in one dispatch.
//   CSR build: zero, hist, scan1, scan23, scatter, sort_csr (canonical).
//   gemm_mfma<AF32>: C[fp16] = A @ W^T, single-pass 16x16x32_f16 MFMA.
//     r9: 64x256 tile (full output width) — A read ONCE (r7's 128x128 with
//     blockIdx.y=2 read A twice); AF32=true converts x fp32->f16 in staging
//     (same rounding as the old convert_h8 pass -> bitwise identical hp),
//     killing the 77MB convert dispatch.
//   scompute: wave-per-node, ushort4-vectorized.
//   aggregate4: wave-per-node fused softmax-stats + gather-aggregate.
//     Determinism: scatter's atomicAdd permutes segments per call; sort_csr
//     canonicalizes -> bitwise-identical output every call (tripwire).
//     FROZEN at the r7 form (70.5us): r4 (wider footprint), r6 (rotating
//     prefetch), r8 (x2 unroll) ALL regressed — the compiler's schedule of
//     the simple 4-edges/iter loop at VGPR=32 is the floor for this
//     structure. Do not restructure the gather loop again.
// ---------------------------------------------------------------------------

typedef __attribute__((ext_vector_type(8))) short short8;
typedef __attribute__((ext_vector_type(8))) unsigned short ushort8;
typedef __attribute__((ext_vector_type(4))) float f32x4;           // MFMA acc
typedef _Float16 half8 __attribute__((ext_vector_type(8)));        // 8 x fp16

__device__ inline unsigned short f2h(float f) {
    _Float16 h = (_Float16)f;
    unsigned short u;
    __builtin_memcpy(&u, &h, 2);
    return u;
}
__device__ inline float h2f(unsigned short u) {
    _Float16 h;
    __builtin_memcpy(&h, &u, 2);
    return (float)h;
}

// both 65536-elem weight matrices in one dispatch: blocks 0..31 -> W1, 32..63 -> W2
__global__ void convert_w2(const float* __restrict__ WA, const float* __restrict__ WB,
                           unsigned short* __restrict__ DA, unsigned short* __restrict__ DB) {
    const bool second = blockIdx.x >= 32;
    const float* S = second ? WB : WA;
    unsigned short* D = second ? DB : DA;
    long i = ((long)(blockIdx.x & 31) * 256 + threadIdx.x) * 8;   // exact fit 65536
    float4 v0 = *(const float4*)&S[i];
    float4 v1 = *(const float4*)&S[i + 4];
    ushort8 o;
    o[0] = f2h(v0.x); o[1] = f2h(v0.y); o[2] = f2h(v0.z); o[3] = f2h(v0.w);
    o[4] = f2h(v1.x); o[5] = f2h(v1.y); o[6] = f2h(v1.z); o[7] = f2h(v1.w);
    *(ushort8*)&D[i] = o;
}

// C[M x 256] (fp16) = A[M x 256] @ B^T (fp16), single-pass f16 MFMA.
// 64x256 tile, BK=32, 4 waves; each wave: 1 m-frag x 16 n-frags (16 rows x
// all 256 cols). A is read exactly once across the grid. Pad-40 LDS rows:
// b128 reads are 2-way bank aliased = free.
// AF32: A is fp32, converted to f16 during staging (bitwise == pre-convert).
template <bool AF32>
__global__ __launch_bounds__(256) void gemm_mfma(const void* __restrict__ A_gv,
                                                 const unsigned short* __restrict__ B_g,
                                                 unsigned short* __restrict__ C, int M) {
    __shared__ unsigned short Ah[64 * 40];
    __shared__ unsigned short Bh[256 * 40];
    const int tid = threadIdx.x;
    const int m0 = blockIdx.x * 64;
    const int w = tid >> 6, lane = tid & 63;
    const int l15 = lane & 15, q = lane >> 4;

    f32x4 acc[16];
    #pragma unroll
    for (int nt = 0; nt < 16; ++nt) acc[nt] = (f32x4){0.f, 0.f, 0.f, 0.f};

    const int ar = tid >> 2;          // 0..63 (A row within tile)
    const int ak = (tid & 3) * 8;     // 0/8/16/24 (k-offset, 8 elems)

    for (int k0 = 0; k0 < 256; k0 += 32) {
        int gm = m0 + ar;
        ushort8 aval;
        if (gm < M) {
            if constexpr (AF32) {
                const float* A_g = (const float*)A_gv;
                const float* ap = &A_g[(size_t)gm * 256 + k0 + ak];
                float4 v0 = *(const float4*)(ap);
                float4 v1 = *(const float4*)(ap + 4);
                aval[0] = f2h(v0.x); aval[1] = f2h(v0.y);
                aval[2] = f2h(v0.z); aval[3] = f2h(v0.w);
                aval[4] = f2h(v1.x); aval[5] = f2h(v1.y);
                aval[6] = f2h(v1.z); aval[7] = f2h(v1.w);
            } else {
                const unsigned short* A_g = (const unsigned short*)A_gv;
                aval = *(const ushort8*)&A_g[(size_t)gm * 256 + k0 + ak];
            }
        } else {
            aval = (ushort8){0, 0, 0, 0, 0, 0, 0, 0};
        }
        *(ushort8*)&Ah[ar * 40 + ak] = aval;
        {
            const unsigned short* b0 = &B_g[(size_t)tid * 256 + k0];
            *(ushort8*)&Bh[tid * 40 + 0]  = *(const ushort8*)(b0);
            *(ushort8*)&Bh[tid * 40 + 8]  = *(const ushort8*)(b0 + 8);
            *(ushort8*)&Bh[tid * 40 + 16] = *(const ushort8*)(b0 + 16);
            *(ushort8*)&Bh[tid * 40 + 24] = *(const ushort8*)(b0 + 24);
        }
        __syncthreads();
        int rowA = w * 16 + l15;
        half8 a = *(half8*)&Ah[rowA * 40 + q * 8];
        #pragma unroll
        for (int nt = 0; nt < 16; ++nt) {
            int rowB = nt * 16 + l15;
            half8 bf = *(half8*)&Bh[rowB * 40 + q * 8];
            acc[nt] = __builtin_amdgcn_mfma_f32_16x16x32_f16(a, bf, acc[nt], 0, 0, 0);
        }
        __syncthreads();
    }
    #pragma unroll
    for (int nt = 0; nt < 16; ++nt) {
        #pragma unroll
        for (int r = 0; r < 4; ++r) {
            int gm = m0 + w * 16 + q * 4 + r;
            if (gm < M) C[(size_t)gm * 256 + nt * 16 + l15] = f2h(acc[nt][r]);
        }
    }
}

// -------------------- CSR build --------------------
__global__ void zero_int(int* __restrict__ p, int n) {
    int i = blockIdx.x * 256 + threadIdx.x;
    if (i < n) p[i] = 0;
}

__global__ void hist_kernel(const int* __restrict__ dst, int* __restrict__ deg, int E) {
    int i = blockIdx.x * 256 + threadIdx.x;
    if (i < E) atomicAdd(&deg[dst[i]], 1);
}

__global__ __launch_bounds__(1024) void scan1(const int* __restrict__ deg,
                                              int* __restrict__ lex,
                                              int* __restrict__ bsums, int n) {
    __shared__ int sh[1024];
    int tid = threadIdx.x;
    int i = blockIdx.x * 1024 + tid;
    int v = (i < n) ? deg[i] : 0;
    sh[tid] = v;
    __syncthreads();
    #pragma unroll
    for (int off = 1; off < 1024; off <<= 1) {
        int t2 = (tid >= off) ? sh[tid - off] : 0;
        __syncthreads();
        sh[tid] += t2;
        __syncthreads();
    }
    if (i < n) lex[i] = sh[tid] - v;
    if (tid == 1023) bsums[blockIdx.x] = sh[1023];
}

// merged scan2+scan3: first wave scans the <=64 block sums, then the block
// applies its exclusive offset. Block 0 also writes offs[n] = grand total.
__global__ __launch_bounds__(1024) void scan23(int* __restrict__ offs,
                                               int* __restrict__ cur,
                                               const int* __restrict__ bsums,
                                               int n, int nb) {
    __shared__ int s_boff, s_total;
    int tid = threadIdx.x;
    if (tid < 64) {
        int bv = (tid < nb) ? bsums[tid] : 0;
        int v = bv;
        #pragma unroll
        for (int off = 1; off < 64; off <<= 1) {
            int t = __shfl_up(v, off, 64);
            if (tid >= off) v += t;
        }
        int incl_bid = __shfl(v, blockIdx.x, 64);
        int bv_bid   = __shfl(bv, blockIdx.x, 64);
        int total    = __shfl(v, nb - 1, 64);
        if (tid == 0) {
            s_boff = incl_bid - bv_bid;   // exclusive prefix for this block
            s_total = total;
        }
    }
    __syncthreads();
    int i = blockIdx.x * 1024 + tid;
    if (i < n) {
        int o = offs[i] + s_boff;
        offs[i] = o;
        cur[i] = o;
    }
    if (blockIdx.x == 0 && tid == 0) offs[n] = s_total;
}

__global__ void scatter_kernel(const int* __restrict__ src, const int* __restrict__ dst,
                               int* __restrict__ cur, int* __restrict__ sorted, int E) {
    int i = blockIdx.x * 256 + threadIdx.x;
    if (i < E) {
        int p = atomicAdd(&cur[dst[i]], 1);
        sorted[p] = src[i];
    }
}

// Canonicalize each CSR segment (deg<=64) with a 64-lane bitonic sort.
// deg>64 segments are left as-is (aggregate4's big path is order-invariant).
// No barriers -> per-wave early return is safe.
__global__ __launch_bounds__(256) void sort_csr(const int* __restrict__ offs,
                                                int* __restrict__ sorted, int N) {
    const int w = threadIdx.x >> 6, lane = threadIdx.x & 63;
    const int node = blockIdx.x * 4 + w;
    if (node >= N) return;
    const int b = offs[node], e = offs[node + 1];
    const int deg = e - b;
    if (deg < 2 || deg > 64) return;
    int key = (lane < deg) ? sorted[b + lane] : 0x7FFFFFFF;
    #pragma unroll
    for (int k = 2; k <= 64; k <<= 1) {
        #pragma unroll
        for (int j = k >> 1; j > 0; j >>= 1) {
            int other = __shfl_xor(key, j, 64);
            bool keepMin = ((lane & j) == 0) == ((lane & k) == 0);
            int mn = min(key, other), mh = max(key, other);
            key = keepMin ? mn : mh;
        }
    }
    if (lane < deg) sorted[b + lane] = key;
}

// -------------------- attention scalars (fp16 hp in) --------------------
// Wave per node, 4 nodes/block. Lane covers 4 contiguous features (8B
// ushort4 load). Fixed-order butterflies -> deterministic.
template <int NH>
__global__ __launch_bounds__(256) void scompute(const unsigned short* __restrict__ hp,
                                                const float* __restrict__ a_src,
                                                const float* __restrict__ a_dst,
                                                float* __restrict__ s_src,
                                                float* __restrict__ s_dst, int N) {
    const int w = threadIdx.x >> 6, lane = threadIdx.x & 63;
    const int node = blockIdx.x * 4 + w;
    if (node >= N) return;          // no barriers below — safe
    const int f0 = lane * 4;
    ushort4 uv = *(const ushort4*)(hp + (size_t)node * 256 + f0);
    float4 as = *(const float4*)(a_src + f0);
    float4 ad = *(const float4*)(a_dst + f0);
    float x0 = h2f(uv.x), x1 = h2f(uv.y), x2 = h2f(uv.z), x3 = h2f(uv.w);
    float p1 = x0 * as.x + x1 * as.y + x2 * as.z + x3 * as.w;
    float p2 = x0 * ad.x + x1 * ad.y + x2 * ad.z + x3 * ad.w;
    if constexpr (NH == 4) {
        #pragma unroll
        for (int off = 1; off < 16; off <<= 1) {
            p1 += __shfl_xor(p1, off, 64);
            p2 += __shfl_xor(p2, off, 64);
        }
        if ((lane & 15) == 0) {
            s_src[node * 4 + (lane >> 4)] = p1;
            s_dst[node * 4 + (lane >> 4)] = p2;
        }
    } else {
        #pragma unroll
        for (int off = 1; off < 64; off <<= 1) {
            p1 += __shfl_xor(p1, off, 64);
            p2 += __shfl_xor(p2, off, 64);
        }
        if (lane == 0) {
            s_src[node] = p1;
            s_dst[node] = p2;
        }
    }
}

// -------------------- fused stats + aggregation (bitwise-deterministic) ----
// One wave per node, 4 nodes per block. CSR segments are pre-sorted
// (sort_csr) so order is canonical. Stats phase computes pv per edge,
// stores (src, pv[]) to LDS. One barrier. Gather: 4 edges/iter, 16 lanes
// x 16 features per edge — FROZEN r7 form (see header note).
// F16OUT=true: write output as fp16 (A-operand of the next GEMM).
template <int NH, bool RELU, bool F16OUT>
__global__ __launch_bounds__(256) void aggregate4(const unsigned short* __restrict__ hp,
                                                  const float* __restrict__ ssrc,
                                                  const float* __restrict__ sdst,
                                                  const int* __restrict__ offs,
                                                  const int* __restrict__ sorted,
                                                  float* __restrict__ out,
                                                  unsigned short* __restrict__ outh, int N) {
    __shared__ int   s_sh[4][64];
    __shared__ float p_sh[4][64][NH];

    const int w = threadIdx.x >> 6, lane = threadIdx.x & 63;
    const int node_raw = blockIdx.x * 4 + w;
    const bool node_ok = node_raw < N;
    const int node = node_ok ? node_raw : (N - 1);   // clamp; no early return
    constexpr int NF = 256 / NH;

    const int b = offs[node], e = offs[node + 1];
    const int deg = e - b;

    float sv[NH];
    #pragma unroll
    for (int h = 0; h < NH; ++h) sv[h] = sdst[node * NH + h];

    float lv[NH], mx[NH];
    const bool small = (deg <= 64);

    if (small) {
        const bool valid = lane < deg;
        const int mys = valid ? sorted[b + lane] : 0;   // pre-sorted ascending

        // ---- stats on sorted sequence ----
        float evv[NH];
        if constexpr (NH == 4) {
            float4 sa = *(const float4*)&ssrc[(size_t)mys * 4];
            evv[0] = sa.x + sv[0]; evv[1] = sa.y + sv[1];
            evv[2] = sa.z + sv[2]; evv[3] = sa.w + sv[3];
        } else {
            evv[0] = ssrc[mys] + sv[0];
        }
        #pragma unroll
        for (int h = 0; h < NH; ++h) {
            float ev = evv[h];
            ev = ev > 0.f ? ev : 0.2f * ev;
            evv[h] = valid ? ev : -INFINITY;
            mx[h] = evv[h];
        }
        #pragma unroll
        for (int off = 32; off > 0; off >>= 1)
            #pragma unroll
            for (int h = 0; h < NH; ++h)
                mx[h] = fmaxf(mx[h], __shfl_xor(mx[h], off, 64));

        float pv[NH];
        #pragma unroll
        for (int h = 0; h < NH; ++h) {
            pv[h] = valid ? __expf(evv[h] - mx[h]) : 0.f;
            lv[h] = pv[h];
        }
        #pragma unroll
        for (int off = 32; off > 0; off >>= 1)
            #pragma unroll
            for (int h = 0; h < NH; ++h)
                lv[h] += __shfl_xor(lv[h], off, 64);

        // stash sorted (src, pv[]) for the gather phase
        s_sh[w][lane] = mys;
        #pragma unroll
        for (int h = 0; h < NH; ++h) p_sh[w][lane][h] = pv[h];
    } else {
        // ---- deg > 64 (never populated for this graph; kept correct) ----
        #pragma unroll
        for (int h = 0; h < NH; ++h) mx[h] = -INFINITY;
        for (int c = b + lane; c < e; c += 64) {
            int s = sorted[c];
            #pragma unroll
            for (int h = 0; h < NH; ++h) {
                float ev = ssrc[s * NH + h] + sv[h];
                ev = ev > 0.f ? ev : 0.2f * ev;
                mx[h] = fmaxf(mx[h], ev);   // max is order-invariant
            }
        }
        #pragma unroll
        for (int off = 32; off > 0; off >>= 1)
            #pragma unroll
            for (int h = 0; h < NH; ++h)
                mx[h] = fmaxf(mx[h], __shfl_xor(mx[h], off, 64));
    }

    __syncthreads();   // all waves reach this exactly once

    if (small) {
        // ---- gather: 4 edges/iter; 16 lanes x 16 features per edge ----
        const int quarter = lane >> 4;
        const int l16 = lane & 15;
        const int f0 = l16 * 16;
        const int head = f0 / NF;        // NH=4: l16/4; NH=1: 0

        float acc[16];
        #pragma unroll
        for (int k = 0; k < 16; ++k) acc[k] = 0.f;

        const int iters = (deg + 3) >> 2;
        for (int t2 = 0; t2 < iters; ++t2) {
            int j = 4 * t2 + quarter;
            bool jv = j < deg;
            int jj = jv ? j : 0;
            int s = s_sh[w][jj];
            float p = jv ? p_sh[w][jj][head] : 0.f;
            const unsigned short* row = hp + (size_t)s * 256 + f0;
            half8 v0 = *(const half8*)(row);
            half8 v1 = *(const half8*)(row + 8);
            #pragma unroll
            for (int k = 0; k < 8; ++k) {
                acc[k]     = fmaf(p, (float)v0[k], acc[k]);
                acc[8 + k] = fmaf(p, (float)v1[k], acc[8 + k]);
            }
        }
        // reduce across the 4 edge-quarters (wave-uniform, all lanes active)
        #pragma unroll
        for (int k = 0; k < 16; ++k) {
            acc[k] += __shfl_xor(acc[k], 16, 64);
            acc[k] += __shfl_xor(acc[k], 32, 64);
        }
        if (node_ok && lane < 16) {
            float li = 1.0f / (lv[head] + 1e-16f);
            float o[16];
            #pragma unroll
            for (int k = 0; k < 16; ++k) {
                o[k] = acc[k] * li;
                if (RELU) o[k] = fmaxf(o[k], 0.f);
            }
            if constexpr (F16OUT) {
                ushort8 u0, u1;
                #pragma unroll
                for (int k = 0; k < 8; ++k) {
                    u0[k] = f2h(o[k]);
                    u1[k] = f2h(o[8 + k]);
                }
                *(ushort8*)&outh[(size_t)node * 256 + f0]     = u0;
                *(ushort8*)&outh[(size_t)node * 256 + f0 + 8] = u1;
            } else {
                float* op = &out[(size_t)node * 256 + f0];
                *(float4*)&op[0]  = make_float4(o[0], o[1], o[2], o[3]);
                *(float4*)&op[4]  = make_float4(o[4], o[5], o[6], o[7]);
                *(float4*)&op[8]  = make_float4(o[8], o[9], o[10], o[11]);
                *(float4*)&op[12] = make_float4(o[12], o[13], o[14], o[15]);
            }
        }
    } else {
        // ---- deg > 64 deterministic ascending-src sweep (rare path) ----
        const int half = lane >> 5;
        const int l32 = lane & 31;
        const int f0 = l32 * 8;
        const int head = f0 / NF;

        float acc[8];
        #pragma unroll
        for (int k = 0; k < 8; ++k) acc[k] = 0.f;
        #pragma unroll
        for (int h = 0; h < NH; ++h) lv[h] = 0.f;

        int last = -1, round = 0;
        for (;;) {
            int myMin = 0x7FFFFFFF, myCnt = 0;
            for (int c = b + lane; c < e; c += 64) {
                int s = sorted[c];
                if (s > last) {
                    if (s < myMin) { myMin = s; myCnt = 1; }
                    else if (s == myMin) ++myCnt;
                }
            }
            #pragma unroll
            for (int off = 32; off > 0; off >>= 1) {
                int om = __shfl_xor(myMin, off, 64);
                int oc = __shfl_xor(myCnt, off, 64);
                if (om < myMin) { myMin = om; myCnt = oc; }
                else if (om == myMin) myCnt += oc;
            }
            if (myMin == 0x7FFFFFFF) break;     // wave-uniform exit
            const bool mine = ((round & 1) == half);
            float cf = (float)myCnt;
            float ph[NH];
            #pragma unroll
            for (int h = 0; h < NH; ++h) {
                float ev = ssrc[myMin * NH + h] + sv[h];
                ev = ev > 0.f ? ev : 0.2f * ev;
                ph[h] = __expf(ev - mx[h]);
            }
            if (mine && l32 == 0) {             // one lane per half owns lv
                #pragma unroll
                for (int h = 0; h < NH; ++h) lv[h] += cf * ph[h];
            }
            if (mine) {
                float p = cf * ph[head];
                half8 v = *(const half8*)(hp + (size_t)myMin * 256 + f0);
                #pragma unroll
                for (int k = 0; k < 8; ++k) acc[k] = fmaf(p, (float)v[k], acc[k]);
            }
            last = myMin; ++round;
        }
        #pragma unroll
        for (int off = 32; off > 0; off >>= 1)
            #pragma unroll
            for (int h = 0; h < NH; ++h)
                lv[h] += __shfl_xor(lv[h], off, 64);

        #pragma unroll
        for (int k = 0; k < 8; ++k) acc[k] += __shfl_xor(acc[k], 32, 64);

        if (node_ok && lane < 32) {
            float li = 1.0f / (lv[head] + 1e-16f);
            float o[8];
            #pragma unroll
            for (int k = 0; k < 8; ++k) {
                o[k] = acc[k] * li;
                if (RELU) o[k] = fmaxf(o[k], 0.f);
            }
            if constexpr (F16OUT) {
                ushort8 u0;
                #pragma unroll
                for (int k = 0; k < 8; ++k) u0[k] = f2h(o[k]);
                *(ushort8*)&outh[(size_t)node * 256 + f0] = u0;
            } else {
                *(float4*)&out[(size_t)node * 256 + f0]     = make_float4(o[0], o[1], o[2], o[3]);
                *(float4*)&out[(size_t)node * 256 + f0 + 4] = make_float4(o[4], o[5], o[6], o[7]);
            }
        }
    }
}

// ---------------------------------------------------------------------------
extern "C" void kernel_launch(void* const* d_in, const int* in_sizes, int n_in,
                              void* d_out, int out_size, void* d_ws, size_t ws_size,
                              hipStream_t stream) {
    const float* x   = (const float*)d_in[0];
    const int*   ei  = (const int*)d_in[1];
    const float* W1  = (const float*)d_in[2];
    const float* a1s = (const float*)d_in[3];
    const float* a1d = (const float*)d_in[4];
    const float* W2  = (const float*)d_in[5];
    const float* a2s = (const float*)d_in[6];
    const float* a2d = (const float*)d_in[7];
    float* out = (float*)d_out;

    const int N = in_sizes[0] / 256;
    const int E = in_sizes[1] / 2;
    const int* src = ei;
    const int* dst = ei + E;

    // workspace carve-up
    unsigned short* hp = (unsigned short*)d_ws;     // N*256 fp16
    float* ssrc  = (float*)(hp + (size_t)N * 256);  // N*4
    float* sdst  = ssrc + (size_t)N * 4;            // N*4
    int*   deg   = (int*)(sdst + (size_t)N * 4);    // N
    int*   cur   = deg + N;                         // N
    int*   offs  = cur + N;                         // N+1
    int*   sorted= offs + N + 1;                    // E
    int*   bsums = sorted + E;                      // 64
    int*   boffs = bsums + 64;                      // 64 (unused, kept for layout)
    unsigned short* w1h = (unsigned short*)(boffs + 64);  // 65536 fp16
    unsigned short* w2h = w1h + 65536;                    // 65536 fp16

    // d_out doubles as fp16 scratch: hh (layer-1 output = layer-2 A) lives in
    // the first half; dead before the final aggregate overwrites d_out fp32.
    unsigned short* hh = (unsigned short*)d_out;    // N*256 fp16

    const int nb = (N + 1023) / 1024;

    // ---- weight fp16 conversion (x converts in-gemm) ----
    convert_w2<<<64, 256, 0, stream>>>(W1, W2, w1h, w2h);

    // ---- CSR build ----
    zero_int<<<(N + 255) / 256, 256, 0, stream>>>(deg, N);
    hist_kernel<<<(E + 255) / 256, 256, 0, stream>>>(dst, deg, E);
    scan1<<<nb, 1024, 0, stream>>>(deg, offs, bsums, N);
    scan23<<<nb, 1024, 0, stream>>>(offs, cur, bsums, N, nb);
    scatter_kernel<<<(E + 255) / 256, 256, 0, stream>>>(src, dst, cur, sorted, E);

    int gemmblocks = (N + 63) / 64;
    int aggblocks = (N + 3) / 4;
    sort_csr<<<aggblocks, 256, 0, stream>>>(offs, sorted, N);

    // ---- layer 1 ----
    gemm_mfma<true><<<gemmblocks, 256, 0, stream>>>(x, w1h, hp, N);
    scompute<4><<<aggblocks, 256, 0, stream>>>(hp, a1s, a1d, ssrc, sdst, N);
    aggregate4<4, true, true><<<aggblocks, 256, 0, stream>>>(hp, ssrc, sdst, offs, sorted,
                                                             nullptr, hh, N);

    // ---- layer 2 ----
    gemm_mfma<false><<<gemmblocks, 256, 0, stream>>>(hh, w2h, hp, N);
    scompute<1><<<aggblocks, 256, 0, stream>>>(hp, a2s, a2d, ssrc, sdst, N);
    aggregate4<1, false, false><<<aggblocks, 256, 0, stream>>>(hp, ssrc, sdst, offs, sorted,
                                                               out, nullptr, N);
}

// Round 10
// 383.004 us; speedup vs baseline: 1.0997x; 1.0837x over previous
//
#include <hip/hip_runtime.h>
#include <math.h>

// ---------------------------------------------------------------------------
// GAT 2-layer pipeline for MI355X.
// N=50000 nodes, E=850000 edges (incl self loops), feat 256, H=4 x 64 -> 256.
//
//   prep: zero(deg) + both W fp32->fp16 in ONE dispatch.
//   CSR build: hist, scan1, scan23, scatter, sort_csr (canonical order).
//   gemm_sc<AF32,NH>: C[fp16] = A @ W^T (single-pass f16 MFMA, 128x256 tile,
//     8 waves: ds_read:MFMA = 10:16, A read once, B read once/block) with the
//     attention scalars (scompute) FUSED into the epilogue from fp32 accs
//     via fixed butterfly trees (deterministic). r10: kills 2 scompute
//     dispatches + 2 full hp re-reads.
//   aggregate4: wave-per-node fused softmax-stats + gather-aggregate.
//     Determinism: scatter's atomicAdd permutes segments per call; sort_csr
//     canonicalizes -> bitwise-identical output every call (tripwire).
//     FROZEN r7 form (70.5us): r4 (wider footprint), r6 (rotating prefetch),
//     r8 (x2 unroll) ALL regressed. Do not restructure the gather loop.
// ---------------------------------------------------------------------------

typedef __attribute__((ext_vector_type(8))) unsigned short ushort8;
typedef __attribute__((ext_vector_type(4))) float f32x4;           // MFMA acc
typedef _Float16 half8 __attribute__((ext_vector_type(8)));        // 8 x fp16

__device__ inline unsigned short f2h(float f) {
    _Float16 h = (_Float16)f;
    unsigned short u;
    __builtin_memcpy(&u, &h, 2);
    return u;
}
__device__ inline float h2f(unsigned short u) {
    _Float16 h;
    __builtin_memcpy(&h, &u, 2);
    return (float)h;
}

// zero(deg) + both 65536-elem weight matrices fp32->fp16, one dispatch.
// Blocks 0..31 convert W1, 32..63 convert W2; all blocks zero deg range.
__global__ void prep(const float* __restrict__ WA, const float* __restrict__ WB,
                     unsigned short* __restrict__ DA, unsigned short* __restrict__ DB,
                     int* __restrict__ deg, int N) {
    int i = blockIdx.x * 256 + threadIdx.x;
    if (i < N) deg[i] = 0;
    if (blockIdx.x < 64) {
        const bool second = blockIdx.x >= 32;
        const float* S = second ? WB : WA;
        unsigned short* D = second ? DB : DA;
        long j = ((long)(blockIdx.x & 31) * 256 + threadIdx.x) * 8;  // exact fit
        float4 v0 = *(const float4*)&S[j];
        float4 v1 = *(const float4*)&S[j + 4];
        ushort8 o;
        o[0] = f2h(v0.x); o[1] = f2h(v0.y); o[2] = f2h(v0.z); o[3] = f2h(v0.w);
        o[4] = f2h(v1.x); o[5] = f2h(v1.y); o[6] = f2h(v1.z); o[7] = f2h(v1.w);
        *(ushort8*)&D[j] = o;
    }
}

// C[M x 256] (fp16) = A[M x 256] @ B^T (fp16) + fused attention scalars.
// 128x256 tile, BK=32, 8 waves (512 thr): wave (wm=w>>1, wn=w&1) owns rows
// [wm*32, wm*32+32) x cols [wn*128, wn*128+128): 2 A-frags x 8 B-frags per
// K-step (ds_read:MFMA = 10:16). A read once across grid; B once per block.
// Pad-40 LDS rows: b128 reads 2-way bank aliased = free.
// Epilogue: writes C fp16 AND s_src/s_dst from fp32 accs (fixed butterfly
// trees -> deterministic). NH=4: each wn half owns 2 complete heads.
// NH=1: cross-half partial combined via LDS in fixed order.
// AF32: A is fp32, converted f16 in staging (bitwise == separate pass).
template <bool AF32, int NH>
__global__ __launch_bounds__(512) void gemm_sc(const void* __restrict__ A_gv,
                                               const unsigned short* __restrict__ B_g,
                                               unsigned short* __restrict__ C,
                                               const float* __restrict__ a_src,
                                               const float* __restrict__ a_dst,
                                               float* __restrict__ s_src,
                                               float* __restrict__ s_dst, int M) {
    __shared__ unsigned short Ah[128 * 40];
    __shared__ unsigned short Bh[256 * 40];
    const int tid = threadIdx.x;
    const int m0 = blockIdx.x * 128;
    const int w = tid >> 6, lane = tid & 63;
    const int wm = w >> 1, wn = w & 1;
    const int l15 = lane & 15, q = lane >> 4;

    f32x4 acc[2][8];
    #pragma unroll
    for (int mt = 0; mt < 2; ++mt)
        #pragma unroll
        for (int nt = 0; nt < 8; ++nt) acc[mt][nt] = (f32x4){0.f, 0.f, 0.f, 0.f};

    const int ar = tid >> 2;          // 0..127 (A row in tile)
    const int ak = (tid & 3) * 8;     // 0/8/16/24
    const int br = tid >> 1;          // 0..255 (B row = out col)
    const int bk = (tid & 1) * 16;    // 0/16

    for (int k0 = 0; k0 < 256; k0 += 32) {
        int gm = m0 + ar;
        ushort8 aval;
        if (gm < M) {
            if constexpr (AF32) {
                const float* A_g = (const float*)A_gv;
                const float* ap = &A_g[(size_t)gm * 256 + k0 + ak];
                float4 v0 = *(const float4*)(ap);
                float4 v1 = *(const float4*)(ap + 4);
                aval[0] = f2h(v0.x); aval[1] = f2h(v0.y);
                aval[2] = f2h(v0.z); aval[3] = f2h(v0.w);
                aval[4] = f2h(v1.x); aval[5] = f2h(v1.y);
                aval[6] = f2h(v1.z); aval[7] = f2h(v1.w);
            } else {
                const unsigned short* A_g = (const unsigned short*)A_gv;
                aval = *(const ushort8*)&A_g[(size_t)gm * 256 + k0 + ak];
            }
        } else {
            aval = (ushort8){0, 0, 0, 0, 0, 0, 0, 0};
        }
        *(ushort8*)&Ah[ar * 40 + ak] = aval;
        {
            const unsigned short* b0 = &B_g[(size_t)br * 256 + k0 + bk];
            *(ushort8*)&Bh[br * 40 + bk]     = *(const ushort8*)(b0);
            *(ushort8*)&Bh[br * 40 + bk + 8] = *(const ushort8*)(b0 + 8);
        }
        __syncthreads();
        half8 a[2];
        #pragma unroll
        for (int mt = 0; mt < 2; ++mt) {
            int rowA = wm * 32 + mt * 16 + l15;
            a[mt] = *(half8*)&Ah[rowA * 40 + q * 8];
        }
        #pragma unroll
        for (int nt = 0; nt < 8; ++nt) {
            int rowB = wn * 128 + nt * 16 + l15;
            half8 bf = *(half8*)&Bh[rowB * 40 + q * 8];
            #pragma unroll
            for (int mt = 0; mt < 2; ++mt)
                acc[mt][nt] = __builtin_amdgcn_mfma_f32_16x16x32_f16(a[mt], bf, acc[mt][nt], 0, 0, 0);
        }
        __syncthreads();
    }

    // ---- C write (fp16) ----
    #pragma unroll
    for (int mt = 0; mt < 2; ++mt) {
        #pragma unroll
        for (int nt = 0; nt < 8; ++nt) {
            #pragma unroll
            for (int r = 0; r < 4; ++r) {
                int gm = m0 + wm * 32 + mt * 16 + q * 4 + r;
                if (gm < M) C[(size_t)gm * 256 + wn * 128 + nt * 16 + l15] = f2h(acc[mt][nt][r]);
            }
        }
    }

    // ---- fused attention scalars ----
    float as[8], ad[8];
    #pragma unroll
    for (int nt = 0; nt < 8; ++nt) {
        int col = wn * 128 + nt * 16 + l15;
        as[nt] = a_src[col];
        ad[nt] = a_dst[col];
    }

    if constexpr (NH == 4) {
        // wn half covers heads {2wn, 2wn+1}: head0 = nt 0..3, head1 = nt 4..7
        #pragma unroll
        for (int mt = 0; mt < 2; ++mt) {
            #pragma unroll
            for (int r = 0; r < 4; ++r) {
                float s0 = 0.f, s1 = 0.f, d0 = 0.f, d1 = 0.f;
                #pragma unroll
                for (int nt = 0; nt < 4; ++nt) {
                    s0 = fmaf(acc[mt][nt][r], as[nt], s0);
                    d0 = fmaf(acc[mt][nt][r], ad[nt], d0);
                }
                #pragma unroll
                for (int nt = 4; nt < 8; ++nt) {
                    s1 = fmaf(acc[mt][nt][r], as[nt], s1);
                    d1 = fmaf(acc[mt][nt][r], ad[nt], d1);
                }
                #pragma unroll
                for (int off = 1; off < 16; off <<= 1) {
                    s0 += __shfl_xor(s0, off, 64);
                    s1 += __shfl_xor(s1, off, 64);
                    d0 += __shfl_xor(d0, off, 64);
                    d1 += __shfl_xor(d1, off, 64);
                }
                int gm = m0 + wm * 32 + mt * 16 + q * 4 + r;
                if (l15 == 0 && gm < M) {
                    s_src[gm * 4 + 2 * wn + 0] = s0;
                    s_src[gm * 4 + 2 * wn + 1] = s1;
                    s_dst[gm * 4 + 2 * wn + 0] = d0;
                    s_dst[gm * 4 + 2 * wn + 1] = d1;
                }
            }
        }
    } else {
        // single head: combine the two wn halves via LDS (fixed order).
        float* part = (float*)Ah;   // reuse: 128 rows x 2 floats = 1KB
        float ss[8], dd[8];
        #pragma unroll
        for (int mt = 0; mt < 2; ++mt) {
            #pragma unroll
            for (int r = 0; r < 4; ++r) {
                float s = 0.f, d = 0.f;
                #pragma unroll
                for (int nt = 0; nt < 8; ++nt) {
                    s = fmaf(acc[mt][nt][r], as[nt], s);
                    d = fmaf(acc[mt][nt][r], ad[nt], d);
                }
                #pragma unroll
                for (int off = 1; off < 16; off <<= 1) {
                    s += __shfl_xor(s, off, 64);
                    d += __shfl_xor(d, off, 64);
                }
                ss[mt * 4 + r] = s;
                dd[mt * 4 + r] = d;
                int rloc = wm * 32 + mt * 16 + q * 4 + r;
                if (wn == 1 && l15 == 0) {
                    part[rloc * 2]     = s;
                    part[rloc * 2 + 1] = d;
                }
            }
        }
        __syncthreads();
        if (wn == 0) {
            #pragma unroll
            for (int mt = 0; mt < 2; ++mt) {
                #pragma unroll
                for (int r = 0; r < 4; ++r) {
                    int rloc = wm * 32 + mt * 16 + q * 4 + r;
                    int gm = m0 + rloc;
                    if (l15 == 0 && gm < M) {
                        s_src[gm] = ss[mt * 4 + r] + part[rloc * 2];
                        s_dst[gm] = dd[mt * 4 + r] + part[rloc * 2 + 1];
                    }
                }
            }
        }
    }
}

// -------------------- CSR build --------------------
__global__ void hist_kernel(const int* __restrict__ dst, int* __restrict__ deg, int E) {
    int i = blockIdx.x * 256 + threadIdx.x;
    if (i < E) atomicAdd(&deg[dst[i]], 1);
}

__global__ __launch_bounds__(1024) void scan1(const int* __restrict__ deg,
                                              int* __restrict__ lex,
                                              int* __restrict__ bsums, int n) {
    __shared__ int sh[1024];
    int tid = threadIdx.x;
    int i = blockIdx.x * 1024 + tid;
    int v = (i < n) ? deg[i] : 0;
    sh[tid] = v;
    __syncthreads();
    #pragma unroll
    for (int off = 1; off < 1024; off <<= 1) {
        int t2 = (tid >= off) ? sh[tid - off] : 0;
        __syncthreads();
        sh[tid] += t2;
        __syncthreads();
    }
    if (i < n) lex[i] = sh[tid] - v;
    if (tid == 1023) bsums[blockIdx.x] = sh[1023];
}

// merged scan2+scan3: first wave scans the <=64 block sums, then the block
// applies its exclusive offset. Block 0 also writes offs[n] = grand total.
__global__ __launch_bounds__(1024) void scan23(int* __restrict__ offs,
                                               int* __restrict__ cur,
                                               const int* __restrict__ bsums,
                                               int n, int nb) {
    __shared__ int s_boff, s_total;
    int tid = threadIdx.x;
    if (tid < 64) {
        int bv = (tid < nb) ? bsums[tid] : 0;
        int v = bv;
        #pragma unroll
        for (int off = 1; off < 64; off <<= 1) {
            int t = __shfl_up(v, off, 64);
            if (tid >= off) v += t;
        }
        int incl_bid = __shfl(v, blockIdx.x, 64);
        int bv_bid   = __shfl(bv, blockIdx.x, 64);
        int total    = __shfl(v, nb - 1, 64);
        if (tid == 0) {
            s_boff = incl_bid - bv_bid;   // exclusive prefix for this block
            s_total = total;
        }
    }
    __syncthreads();
    int i = blockIdx.x * 1024 + tid;
    if (i < n) {
        int o = offs[i] + s_boff;
        offs[i] = o;
        cur[i] = o;
    }
    if (blockIdx.x == 0 && tid == 0) offs[n] = s_total;
}

__global__ void scatter_kernel(const int* __restrict__ src, const int* __restrict__ dst,
                               int* __restrict__ cur, int* __restrict__ sorted, int E) {
    int i = blockIdx.x * 256 + threadIdx.x;
    if (i < E) {
        int p = atomicAdd(&cur[dst[i]], 1);
        sorted[p] = src[i];
    }
}

// Canonicalize each CSR segment (deg<=64) with a 64-lane bitonic sort.
// deg>64 segments are left as-is (aggregate4's big path is order-invariant).
// No barriers -> per-wave early return is safe.
__global__ __launch_bounds__(256) void sort_csr(const int* __restrict__ offs,
                                                int* __restrict__ sorted, int N) {
    const int w = threadIdx.x >> 6, lane = threadIdx.x & 63;
    const int node = blockIdx.x * 4 + w;
    if (node >= N) return;
    const int b = offs[node], e = offs[node + 1];
    const int deg = e - b;
    if (deg < 2 || deg > 64) return;
    int key = (lane < deg) ? sorted[b + lane] : 0x7FFFFFFF;
    #pragma unroll
    for (int k = 2; k <= 64; k <<= 1) {
        #pragma unroll
        for (int j = k >> 1; j > 0; j >>= 1) {
            int other = __shfl_xor(key, j, 64);
            bool keepMin = ((lane & j) == 0) == ((lane & k) == 0);
            int mn = min(key, other), mh = max(key, other);
            key = keepMin ? mn : mh;
        }
    }
    if (lane < deg) sorted[b + lane] = key;
}

// -------------------- fused stats + aggregation (bitwise-deterministic) ----
// One wave per node, 4 nodes per block. CSR segments are pre-sorted
// (sort_csr) so order is canonical. Stats phase computes pv per edge,
// stores (src, pv[]) to LDS. One barrier. Gather: 4 edges/iter, 16 lanes
// x 16 features per edge — FROZEN r7 form (see header note).
// F16OUT=true: write output as fp16 (A-operand of the next GEMM).
template <int NH, bool RELU, bool F16OUT>
__global__ __launch_bounds__(256) void aggregate4(const unsigned short* __restrict__ hp,
                                                  const float* __restrict__ ssrc,
                                                  const float* __restrict__ sdst,
                                                  const int* __restrict__ offs,
                                                  const int* __restrict__ sorted,
                                                  float* __restrict__ out,
                                                  unsigned short* __restrict__ outh, int N) {
    __shared__ int   s_sh[4][64];
    __shared__ float p_sh[4][64][NH];

    const int w = threadIdx.x >> 6, lane = threadIdx.x & 63;
    const int node_raw = blockIdx.x * 4 + w;
    const bool node_ok = node_raw < N;
    const int node = node_ok ? node_raw : (N - 1);   // clamp; no early return
    constexpr int NF = 256 / NH;

    const int b = offs[node], e = offs[node + 1];
    const int deg = e - b;

    float sv[NH];
    #pragma unroll
    for (int h = 0; h < NH; ++h) sv[h] = sdst[node * NH + h];

    float lv[NH], mx[NH];
    const bool small = (deg <= 64);

    if (small) {
        const bool valid = lane < deg;
        const int mys = valid ? sorted[b + lane] : 0;   // pre-sorted ascending

        // ---- stats on sorted sequence ----
        float evv[NH];
        if constexpr (NH == 4) {
            float4 sa = *(const float4*)&ssrc[(size_t)mys * 4];
            evv[0] = sa.x + sv[0]; evv[1] = sa.y + sv[1];
            evv[2] = sa.z + sv[2]; evv[3] = sa.w + sv[3];
        } else {
            evv[0] = ssrc[mys] + sv[0];
        }
        #pragma unroll
        for (int h = 0; h < NH; ++h) {
            float ev = evv[h];
            ev = ev > 0.f ? ev : 0.2f * ev;
            evv[h] = valid ? ev : -INFINITY;
            mx[h] = evv[h];
        }
        #pragma unroll
        for (int off = 32; off > 0; off >>= 1)
            #pragma unroll
            for (int h = 0; h < NH; ++h)
                mx[h] = fmaxf(mx[h], __shfl_xor(mx[h], off, 64));

        float pv[NH];
        #pragma unroll
        for (int h = 0; h < NH; ++h) {
            pv[h] = valid ? __expf(evv[h] - mx[h]) : 0.f;
            lv[h] = pv[h];
        }
        #pragma unroll
        for (int off = 32; off > 0; off >>= 1)
            #pragma unroll
            for (int h = 0; h < NH; ++h)
                lv[h] += __shfl_xor(lv[h], off, 64);

        // stash sorted (src, pv[]) for the gather phase
        s_sh[w][lane] = mys;
        #pragma unroll
        for (int h = 0; h < NH; ++h) p_sh[w][lane][h] = pv[h];
    } else {
        // ---- deg > 64 (never populated for this graph; kept correct) ----
        #pragma unroll
        for (int h = 0; h < NH; ++h) mx[h] = -INFINITY;
        for (int c = b + lane; c < e; c += 64) {
            int s = sorted[c];
            #pragma unroll
            for (int h = 0; h < NH; ++h) {
                float ev = ssrc[s * NH + h] + sv[h];
                ev = ev > 0.f ? ev : 0.2f * ev;
                mx[h] = fmaxf(mx[h], ev);   // max is order-invariant
            }
        }
        #pragma unroll
        for (int off = 32; off > 0; off >>= 1)
            #pragma unroll
            for (int h = 0; h < NH; ++h)
                mx[h] = fmaxf(mx[h], __shfl_xor(mx[h], off, 64));
    }

    __syncthreads();   // all waves reach this exactly once

    if (small) {
        // ---- gather: 4 edges/iter; 16 lanes x 16 features per edge ----
        const int quarter = lane >> 4;
        const int l16 = lane & 15;
        const int f0 = l16 * 16;
        const int head = f0 / NF;        // NH=4: l16/4; NH=1: 0

        float acc[16];
        #pragma unroll
        for (int k = 0; k < 16; ++k) acc[k] = 0.f;

        const int iters = (deg + 3) >> 2;
        for (int t2 = 0; t2 < iters; ++t2) {
            int j = 4 * t2 + quarter;
            bool jv = j < deg;
            int jj = jv ? j : 0;
            int s = s_sh[w][jj];
            float p = jv ? p_sh[w][jj][head] : 0.f;
            const unsigned short* row = hp + (size_t)s * 256 + f0;
            half8 v0 = *(const half8*)(row);
            half8 v1 = *(const half8*)(row + 8);
            #pragma unroll
            for (int k = 0; k < 8; ++k) {
                acc[k]     = fmaf(p, (float)v0[k], acc[k]);
                acc[8 + k] = fmaf(p, (float)v1[k], acc[8 + k]);
            }
        }
        // reduce across the 4 edge-quarters (wave-uniform, all lanes active)
        #pragma unroll
        for (int k = 0; k < 16; ++k) {
            acc[k] += __shfl_xor(acc[k], 16, 64);
            acc[k] += __shfl_xor(acc[k], 32, 64);
        }
        if (node_ok && lane < 16) {
            float li = 1.0f / (lv[head] + 1e-16f);
            float o[16];
            #pragma unroll
            for (int k = 0; k < 16; ++k) {
                o[k] = acc[k] * li;
                if (RELU) o[k] = fmaxf(o[k], 0.f);
            }
            if constexpr (F16OUT) {
                ushort8 u0, u1;
                #pragma unroll
                for (int k = 0; k < 8; ++k) {
                    u0[k] = f2h(o[k]);
                    u1[k] = f2h(o[8 + k]);
                }
                *(ushort8*)&outh[(size_t)node * 256 + f0]     = u0;
                *(ushort8*)&outh[(size_t)node * 256 + f0 + 8] = u1;
            } else {
                float* op = &out[(size_t)node * 256 + f0];
                *(float4*)&op[0]  = make_float4(o[0], o[1], o[2], o[3]);
                *(float4*)&op[4]  = make_float4(o[4], o[5], o[6], o[7]);
                *(float4*)&op[8]  = make_float4(o[8], o[9], o[10], o[11]);
                *(float4*)&op[12] = make_float4(o[12], o[13], o[14], o[15]);
            }
        }
    } else {
        // ---- deg > 64 deterministic ascending-src sweep (rare path) ----
        const int half = lane >> 5;
        const int l32 = lane & 31;
        const int f0 = l32 * 8;
        const int head = f0 / NF;

        float acc[8];
        #pragma unroll
        for (int k = 0; k < 8; ++k) acc[k] = 0.f;
        #pragma unroll
        for (int h = 0; h < NH; ++h) lv[h] = 0.f;

        int last = -1, round = 0;
        for (;;) {
            int myMin = 0x7FFFFFFF, myCnt = 0;
            for (int c = b + lane; c < e; c += 64) {
                int s = sorted[c];
                if (s > last) {
                    if (s < myMin) { myMin = s; myCnt = 1; }
                    else if (s == myMin) ++myCnt;
                }
            }
            #pragma unroll
            for (int off = 32; off > 0; off >>= 1) {
                int om = __shfl_xor(myMin, off, 64);
                int oc = __shfl_xor(myCnt, off, 64);
                if (om < myMin) { myMin = om; myCnt = oc; }
                else if (om == myMin) myCnt += oc;
            }
            if (myMin == 0x7FFFFFFF) break;     // wave-uniform exit
            const bool mine = ((round & 1) == half);
            float cf = (float)myCnt;
            float ph[NH];
            #pragma unroll
            for (int h = 0; h < NH; ++h) {
                float ev = ssrc[myMin * NH + h] + sv[h];
                ev = ev > 0.f ? ev : 0.2f * ev;
                ph[h] = __expf(ev - mx[h]);
            }
            if (mine && l32 == 0) {             // one lane per half owns lv
                #pragma unroll
                for (int h = 0; h < NH; ++h) lv[h] += cf * ph[h];
            }
            if (mine) {
                float p = cf * ph[head];
                half8 v = *(const half8*)(hp + (size_t)myMin * 256 + f0);
                #pragma unroll
                for (int k = 0; k < 8; ++k) acc[k] = fmaf(p, (float)v[k], acc[k]);
            }
            last = myMin; ++round;
        }
        #pragma unroll
        for (int off = 32; off > 0; off >>= 1)
            #pragma unroll
            for (int h = 0; h < NH; ++h)
                lv[h] += __shfl_xor(lv[h], off, 64);

        #pragma unroll
        for (int k = 0; k < 8; ++k) acc[k] += __shfl_xor(acc[k], 32, 64);

        if (node_ok && lane < 32) {
            float li = 1.0f / (lv[head] + 1e-16f);
            float o[8];
            #pragma unroll
            for (int k = 0; k < 8; ++k) {
                o[k] = acc[k] * li;
                if (RELU) o[k] = fmaxf(o[k], 0.f);
            }
            if constexpr (F16OUT) {
                ushort8 u0;
                #pragma unroll
                for (int k = 0; k < 8; ++k) u0[k] = f2h(o[k]);
                *(ushort8*)&outh[(size_t)node * 256 + f0] = u0;
            } else {
                *(float4*)&out[(size_t)node * 256 + f0]     = make_float4(o[0], o[1], o[2], o[3]);
                *(float4*)&out[(size_t)node * 256 + f0 + 4] = make_float4(o[4], o[5], o[6], o[7]);
            }
        }
    }
}

// ---------------------------------------------------------------------------
extern "C" void kernel_launch(void* const* d_in, const int* in_sizes, int n_in,
                              void* d_out, int out_size, void* d_ws, size_t ws_size,
                              hipStream_t stream) {
    const float* x   = (const float*)d_in[0];
    const int*   ei  = (const int*)d_in[1];
    const float* W1  = (const float*)d_in[2];
    const float* a1s = (const float*)d_in[3];
    const float* a1d = (const float*)d_in[4];
    const float* W2  = (const float*)d_in[5];
    const float* a2s = (const float*)d_in[6];
    const float* a2d = (const float*)d_in[7];
    float* out = (float*)d_out;

    const int N = in_sizes[0] / 256;
    const int E = in_sizes[1] / 2;
    const int* src = ei;
    const int* dst = ei + E;

    // workspace carve-up
    unsigned short* hp = (unsigned short*)d_ws;     // N*256 fp16
    float* ssrc  = (float*)(hp + (size_t)N * 256);  // N*4
    float* sdst  = ssrc + (size_t)N * 4;            // N*4
    int*   deg   = (int*)(sdst + (size_t)N * 4);    // N
    int*   cur   = deg + N;                         // N
    int*   offs  = cur + N;                         // N+1
    int*   sorted= offs + N + 1;                    // E
    int*   bsums = sorted + E;                      // 64
    int*   boffs = bsums + 64;                      // 64 (unused, kept for layout)
    unsigned short* w1h = (unsigned short*)(boffs + 64);  // 65536 fp16
    unsigned short* w2h = w1h + 65536;                    // 65536 fp16

    // d_out doubles as fp16 scratch: hh (layer-1 output = layer-2 A) lives in
    // the first half; dead before the final aggregate overwrites d_out fp32.
    unsigned short* hh = (unsigned short*)d_out;    // N*256 fp16

    const int nb = (N + 1023) / 1024;
    const int prepblocks = ((N + 255) / 256) > 64 ? ((N + 255) / 256) : 64;

    // ---- prep: zero(deg) + W fp16 conversion ----
    prep<<<prepblocks, 256, 0, stream>>>(W1, W2, w1h, w2h, deg, N);

    // ---- CSR build ----
    hist_kernel<<<(E + 255) / 256, 256, 0, stream>>>(dst, deg, E);
    scan1<<<nb, 1024, 0, stream>>>(deg, offs, bsums, N);
    scan23<<<nb, 1024, 0, stream>>>(offs, cur, bsums, N, nb);
    scatter_kernel<<<(E + 255) / 256, 256, 0, stream>>>(src, dst, cur, sorted, E);

    int gemmblocks = (N + 127) / 128;
    int aggblocks = (N + 3) / 4;
    sort_csr<<<aggblocks, 256, 0, stream>>>(offs, sorted, N);

    // ---- layer 1 (gemm + fused scompute) ----
    gemm_sc<true, 4><<<gemmblocks, 512, 0, stream>>>(x, w1h, hp, a1s, a1d, ssrc, sdst, N);
    aggregate4<4, true, true><<<aggblocks, 256, 0, stream>>>(hp, ssrc, sdst, offs, sorted,
                                                             nullptr, hh, N);

    // ---- layer 2 (gemm + fused scompute) ----
    gemm_sc<false, 1><<<gemmblocks, 512, 0, stream>>>(hh, w2h, hp, a2s, a2d, ssrc, sdst, N);
    aggregate4<1, false, false><<<aggblocks, 256, 0, stream>>>(hp, ssrc, sdst, offs, sorted,
                                                               out, nullptr, N);
}

// Round 11
// 373.596 us; speedup vs baseline: 1.1274x; 1.0252x over previous
//
#include <hip/hip_runtime.h>
#include <math.h>

// ---------------------------------------------------------------------------
// GAT 2-layer pipeline for MI355X.
// N=50000 nodes, E=850000 edges (incl self loops), feat 256, H=4 x 64 -> 256.
//
//   prep: zero(deg) + both W fp32->fp16 in ONE dispatch.
//   CSR build: hist, scan1 (r11: shuffle-based, 2 barriers), scan23,
//     scatter, sort_csr (canonical ascending-src order per segment).
//   gemm_sc<AF32,NH>: C[fp16] = A @ W^T (single-pass f16 MFMA, 128x256 tile,
//     8 waves, ds_read:MFMA = 10:16, A read once) + scompute fused into the
//     epilogue from fp32 accs via fixed butterfly trees (deterministic).
//   aggregate4: wave-per-node fused softmax-stats + gather-aggregate.
//     Determinism: scatter's atomicAdd permutes segments per call; sort_csr
//     canonicalizes -> bitwise-identical output every call (tripwire).
//     Gather loop FROZEN r7 form: r4 (wider footprint), r6 (prefetch),
//     r8 (x2 unroll) ALL regressed.
//     r11: removed the block __syncthreads — s_sh/p_sh are WAVE-PRIVATE
//     (indexed by w; same wave writes and reads), so no barrier is needed;
//     the barrier made every block wait on its slowest wave (deg~Poisson(17),
//     E[max of 4]/mean ~1.3x straggler tax). Early returns restored.
// ---------------------------------------------------------------------------

typedef __attribute__((ext_vector_type(8))) unsigned short ushort8;
typedef __attribute__((ext_vector_type(4))) float f32x4;           // MFMA acc
typedef _Float16 half8 __attribute__((ext_vector_type(8)));        // 8 x fp16

__device__ inline unsigned short f2h(float f) {
    _Float16 h = (_Float16)f;
    unsigned short u;
    __builtin_memcpy(&u, &h, 2);
    return u;
}
__device__ inline float h2f(unsigned short u) {
    _Float16 h;
    __builtin_memcpy(&h, &u, 2);
    return (float)h;
}

// zero(deg) + both 65536-elem weight matrices fp32->fp16, one dispatch.
__global__ void prep(const float* __restrict__ WA, const float* __restrict__ WB,
                     unsigned short* __restrict__ DA, unsigned short* __restrict__ DB,
                     int* __restrict__ deg, int N) {
    int i = blockIdx.x * 256 + threadIdx.x;
    if (i < N) deg[i] = 0;
    if (blockIdx.x < 64) {
        const bool second = blockIdx.x >= 32;
        const float* S = second ? WB : WA;
        unsigned short* D = second ? DB : DA;
        long j = ((long)(blockIdx.x & 31) * 256 + threadIdx.x) * 8;  // exact fit
        float4 v0 = *(const float4*)&S[j];
        float4 v1 = *(const float4*)&S[j + 4];
        ushort8 o;
        o[0] = f2h(v0.x); o[1] = f2h(v0.y); o[2] = f2h(v0.z); o[3] = f2h(v0.w);
        o[4] = f2h(v1.x); o[5] = f2h(v1.y); o[6] = f2h(v1.z); o[7] = f2h(v1.w);
        *(ushort8*)&D[j] = o;
    }
}

// C[M x 256] (fp16) = A[M x 256] @ B^T (fp16) + fused attention scalars.
// 128x256 tile, BK=32, 8 waves (512 thr): wave (wm,wn) owns 32 rows x 128
// cols: 2 A-frags x 8 B-frags per K-step. Pad-40 LDS rows.
template <bool AF32, int NH>
__global__ __launch_bounds__(512) void gemm_sc(const void* __restrict__ A_gv,
                                               const unsigned short* __restrict__ B_g,
                                               unsigned short* __restrict__ C,
                                               const float* __restrict__ a_src,
                                               const float* __restrict__ a_dst,
                                               float* __restrict__ s_src,
                                               float* __restrict__ s_dst, int M) {
    __shared__ unsigned short Ah[128 * 40];
    __shared__ unsigned short Bh[256 * 40];
    const int tid = threadIdx.x;
    const int m0 = blockIdx.x * 128;
    const int w = tid >> 6, lane = tid & 63;
    const int wm = w >> 1, wn = w & 1;
    const int l15 = lane & 15, q = lane >> 4;

    f32x4 acc[2][8];
    #pragma unroll
    for (int mt = 0; mt < 2; ++mt)
        #pragma unroll
        for (int nt = 0; nt < 8; ++nt) acc[mt][nt] = (f32x4){0.f, 0.f, 0.f, 0.f};

    const int ar = tid >> 2;          // 0..127 (A row in tile)
    const int ak = (tid & 3) * 8;     // 0/8/16/24
    const int br = tid >> 1;          // 0..255 (B row = out col)
    const int bk = (tid & 1) * 16;    // 0/16

    for (int k0 = 0; k0 < 256; k0 += 32) {
        int gm = m0 + ar;
        ushort8 aval;
        if (gm < M) {
            if constexpr (AF32) {
                const float* A_g = (const float*)A_gv;
                const float* ap = &A_g[(size_t)gm * 256 + k0 + ak];
                float4 v0 = *(const float4*)(ap);
                float4 v1 = *(const float4*)(ap + 4);
                aval[0] = f2h(v0.x); aval[1] = f2h(v0.y);
                aval[2] = f2h(v0.z); aval[3] = f2h(v0.w);
                aval[4] = f2h(v1.x); aval[5] = f2h(v1.y);
                aval[6] = f2h(v1.z); aval[7] = f2h(v1.w);
            } else {
                const unsigned short* A_g = (const unsigned short*)A_gv;
                aval = *(const ushort8*)&A_g[(size_t)gm * 256 + k0 + ak];
            }
        } else {
            aval = (ushort8){0, 0, 0, 0, 0, 0, 0, 0};
        }
        *(ushort8*)&Ah[ar * 40 + ak] = aval;
        {
            const unsigned short* b0 = &B_g[(size_t)br * 256 + k0 + bk];
            *(ushort8*)&Bh[br * 40 + bk]     = *(const ushort8*)(b0);
            *(ushort8*)&Bh[br * 40 + bk + 8] = *(const ushort8*)(b0 + 8);
        }
        __syncthreads();
        half8 a[2];
        #pragma unroll
        for (int mt = 0; mt < 2; ++mt) {
            int rowA = wm * 32 + mt * 16 + l15;
            a[mt] = *(half8*)&Ah[rowA * 40 + q * 8];
        }
        #pragma unroll
        for (int nt = 0; nt < 8; ++nt) {
            int rowB = wn * 128 + nt * 16 + l15;
            half8 bf = *(half8*)&Bh[rowB * 40 + q * 8];
            #pragma unroll
            for (int mt = 0; mt < 2; ++mt)
                acc[mt][nt] = __builtin_amdgcn_mfma_f32_16x16x32_f16(a[mt], bf, acc[mt][nt], 0, 0, 0);
        }
        __syncthreads();
    }

    // ---- C write (fp16) ----
    #pragma unroll
    for (int mt = 0; mt < 2; ++mt) {
        #pragma unroll
        for (int nt = 0; nt < 8; ++nt) {
            #pragma unroll
            for (int r = 0; r < 4; ++r) {
                int gm = m0 + wm * 32 + mt * 16 + q * 4 + r;
                if (gm < M) C[(size_t)gm * 256 + wn * 128 + nt * 16 + l15] = f2h(acc[mt][nt][r]);
            }
        }
    }

    // ---- fused attention scalars ----
    float as[8], ad[8];
    #pragma unroll
    for (int nt = 0; nt < 8; ++nt) {
        int col = wn * 128 + nt * 16 + l15;
        as[nt] = a_src[col];
        ad[nt] = a_dst[col];
    }

    if constexpr (NH == 4) {
        // wn half covers heads {2wn, 2wn+1}: head0 = nt 0..3, head1 = nt 4..7
        #pragma unroll
        for (int mt = 0; mt < 2; ++mt) {
            #pragma unroll
            for (int r = 0; r < 4; ++r) {
                float s0 = 0.f, s1 = 0.f, d0 = 0.f, d1 = 0.f;
                #pragma unroll
                for (int nt = 0; nt < 4; ++nt) {
                    s0 = fmaf(acc[mt][nt][r], as[nt], s0);
                    d0 = fmaf(acc[mt][nt][r], ad[nt], d0);
                }
                #pragma unroll
                for (int nt = 4; nt < 8; ++nt) {
                    s1 = fmaf(acc[mt][nt][r], as[nt], s1);
                    d1 = fmaf(acc[mt][nt][r], ad[nt], d1);
                }
                #pragma unroll
                for (int off = 1; off < 16; off <<= 1) {
                    s0 += __shfl_xor(s0, off, 64);
                    s1 += __shfl_xor(s1, off, 64);
                    d0 += __shfl_xor(d0, off, 64);
                    d1 += __shfl_xor(d1, off, 64);
                }
                int gm = m0 + wm * 32 + mt * 16 + q * 4 + r;
                if (l15 == 0 && gm < M) {
                    s_src[gm * 4 + 2 * wn + 0] = s0;
                    s_src[gm * 4 + 2 * wn + 1] = s1;
                    s_dst[gm * 4 + 2 * wn + 0] = d0;
                    s_dst[gm * 4 + 2 * wn + 1] = d1;
                }
            }
        }
    } else {
        // single head: combine the two wn halves via LDS (fixed order).
        float* part = (float*)Ah;   // reuse: 128 rows x 2 floats = 1KB
        float ss[8], dd[8];
        #pragma unroll
        for (int mt = 0; mt < 2; ++mt) {
            #pragma unroll
            for (int r = 0; r < 4; ++r) {
                float s = 0.f, d = 0.f;
                #pragma unroll
                for (int nt = 0; nt < 8; ++nt) {
                    s = fmaf(acc[mt][nt][r], as[nt], s);
                    d = fmaf(acc[mt][nt][r], ad[nt], d);
                }
                #pragma unroll
                for (int off = 1; off < 16; off <<= 1) {
                    s += __shfl_xor(s, off, 64);
                    d += __shfl_xor(d, off, 64);
                }
                ss[mt * 4 + r] = s;
                dd[mt * 4 + r] = d;
                int rloc = wm * 32 + mt * 16 + q * 4 + r;
                if (wn == 1 && l15 == 0) {
                    part[rloc * 2]     = s;
                    part[rloc * 2 + 1] = d;
                }
            }
        }
        __syncthreads();
        if (wn == 0) {
            #pragma unroll
            for (int mt = 0; mt < 2; ++mt) {
                #pragma unroll
                for (int r = 0; r < 4; ++r) {
                    int rloc = wm * 32 + mt * 16 + q * 4 + r;
                    int gm = m0 + rloc;
                    if (l15 == 0 && gm < M) {
                        s_src[gm] = ss[mt * 4 + r] + part[rloc * 2];
                        s_dst[gm] = dd[mt * 4 + r] + part[rloc * 2 + 1];
                    }
                }
            }
        }
    }
}

// -------------------- CSR build --------------------
__global__ void hist_kernel(const int* __restrict__ dst, int* __restrict__ deg, int E) {
    int i = blockIdx.x * 256 + threadIdx.x;
    if (i < E) atomicAdd(&deg[dst[i]], 1);
}

// block-level exclusive scan, shuffle-based (2 barriers). Same integer
// results as the old Hillis-Steele version (addition is exact).
__global__ __launch_bounds__(1024) void scan1(const int* __restrict__ deg,
                                              int* __restrict__ lex,
                                              int* __restrict__ bsums, int n) {
    __shared__ int wsum[16];
    const int tid = threadIdx.x;
    const int wv = tid >> 6, lane = tid & 63;
    const int i = blockIdx.x * 1024 + tid;
    const int v = (i < n) ? deg[i] : 0;
    int s = v;
    #pragma unroll
    for (int off = 1; off < 64; off <<= 1) {
        int t = __shfl_up(s, off, 64);
        if (lane >= off) s += t;
    }
    if (lane == 63) wsum[wv] = s;
    __syncthreads();
    if (wv == 0) {
        int ws = (lane < 16) ? wsum[lane] : 0;
        #pragma unroll
        for (int off = 1; off < 16; off <<= 1) {
            int t = __shfl_up(ws, off, 64);
            if (lane >= off) ws += t;
        }
        if (lane < 16) wsum[lane] = ws;   // inclusive wave prefix
    }
    __syncthreads();
    int base = (wv > 0) ? wsum[wv - 1] : 0;
    int incl = base + s;
    if (i < n) lex[i] = incl - v;         // exclusive
    if (tid == 1023) bsums[blockIdx.x] = incl;
}

// merged scan2+scan3: first wave scans the <=64 block sums, then the block
// applies its exclusive offset. Block 0 also writes offs[n] = grand total.
__global__ __launch_bounds__(1024) void scan23(int* __restrict__ offs,
                                               int* __restrict__ cur,
                                               const int* __restrict__ bsums,
                                               int n, int nb) {
    __shared__ int s_boff, s_total;
    int tid = threadIdx.x;
    if (tid < 64) {
        int bv = (tid < nb) ? bsums[tid] : 0;
        int v = bv;
        #pragma unroll
        for (int off = 1; off < 64; off <<= 1) {
            int t = __shfl_up(v, off, 64);
            if (tid >= off) v += t;
        }
        int incl_bid = __shfl(v, blockIdx.x, 64);
        int bv_bid   = __shfl(bv, blockIdx.x, 64);
        int total    = __shfl(v, nb - 1, 64);
        if (tid == 0) {
            s_boff = incl_bid - bv_bid;   // exclusive prefix for this block
            s_total = total;
        }
    }
    __syncthreads();
    int i = blockIdx.x * 1024 + tid;
    if (i < n) {
        int o = offs[i] + s_boff;
        offs[i] = o;
        cur[i] = o;
    }
    if (blockIdx.x == 0 && tid == 0) offs[n] = s_total;
}

__global__ void scatter_kernel(const int* __restrict__ src, const int* __restrict__ dst,
                               int* __restrict__ cur, int* __restrict__ sorted, int E) {
    int i = blockIdx.x * 256 + threadIdx.x;
    if (i < E) {
        int p = atomicAdd(&cur[dst[i]], 1);
        sorted[p] = src[i];
    }
}

// Canonicalize each CSR segment (deg<=64) with a 64-lane bitonic sort.
// deg>64 segments are left as-is (aggregate4's big path is order-invariant).
__global__ __launch_bounds__(256) void sort_csr(const int* __restrict__ offs,
                                                int* __restrict__ sorted, int N) {
    const int w = threadIdx.x >> 6, lane = threadIdx.x & 63;
    const int node = blockIdx.x * 4 + w;
    if (node >= N) return;
    const int b = offs[node], e = offs[node + 1];
    const int deg = e - b;
    if (deg < 2 || deg > 64) return;
    int key = (lane < deg) ? sorted[b + lane] : 0x7FFFFFFF;
    #pragma unroll
    for (int k = 2; k <= 64; k <<= 1) {
        #pragma unroll
        for (int j = k >> 1; j > 0; j >>= 1) {
            int other = __shfl_xor(key, j, 64);
            bool keepMin = ((lane & j) == 0) == ((lane & k) == 0);
            int mn = min(key, other), mh = max(key, other);
            key = keepMin ? mn : mh;
        }
    }
    if (lane < deg) sorted[b + lane] = key;
}

// -------------------- fused stats + aggregation (bitwise-deterministic) ----
// One wave per node, 4 nodes per block — waves fully independent (r11: no
// block barrier; s_sh/p_sh are wave-private). CSR segments pre-sorted.
// Gather: 4 edges/iter, 16 lanes x 16 features — FROZEN r7 form.
// F16OUT=true: write output as fp16 (A-operand of the next GEMM).
template <int NH, bool RELU, bool F16OUT>
__global__ __launch_bounds__(256) void aggregate4(const unsigned short* __restrict__ hp,
                                                  const float* __restrict__ ssrc,
                                                  const float* __restrict__ sdst,
                                                  const int* __restrict__ offs,
                                                  const int* __restrict__ sorted,
                                                  float* __restrict__ out,
                                                  unsigned short* __restrict__ outh, int N) {
    __shared__ int   s_sh[4][64];
    __shared__ float p_sh[4][64][NH];

    const int w = threadIdx.x >> 6, lane = threadIdx.x & 63;
    const int node = blockIdx.x * 4 + w;
    if (node >= N) return;               // wave-independent: no barriers below
    constexpr int NF = 256 / NH;

    const int b = offs[node], e = offs[node + 1];
    const int deg = e - b;

    if (deg == 0) {   // no edges: output zeros
        if (lane < 16) {
            const int f0 = lane * 16;
            if constexpr (F16OUT) {
                ushort8 z = (ushort8){0, 0, 0, 0, 0, 0, 0, 0};
                *(ushort8*)&outh[(size_t)node * 256 + f0]     = z;
                *(ushort8*)&outh[(size_t)node * 256 + f0 + 8] = z;
            } else {
                float4 z = make_float4(0.f, 0.f, 0.f, 0.f);
                float* op = &out[(size_t)node * 256 + f0];
                *(float4*)&op[0] = z; *(float4*)&op[4] = z;
                *(float4*)&op[8] = z; *(float4*)&op[12] = z;
            }
        }
        return;
    }

    float sv[NH];
    #pragma unroll
    for (int h = 0; h < NH; ++h) sv[h] = sdst[node * NH + h];

    float lv[NH], mx[NH];
    const bool small = (deg <= 64);

    if (small) {
        const bool valid = lane < deg;
        const int mys = valid ? sorted[b + lane] : 0;   // pre-sorted ascending

        // ---- stats on sorted sequence ----
        float evv[NH];
        if constexpr (NH == 4) {
            float4 sa = *(const float4*)&ssrc[(size_t)mys * 4];
            evv[0] = sa.x + sv[0]; evv[1] = sa.y + sv[1];
            evv[2] = sa.z + sv[2]; evv[3] = sa.w + sv[3];
        } else {
            evv[0] = ssrc[mys] + sv[0];
        }
        #pragma unroll
        for (int h = 0; h < NH; ++h) {
            float ev = evv[h];
            ev = ev > 0.f ? ev : 0.2f * ev;
            evv[h] = valid ? ev : -INFINITY;
            mx[h] = evv[h];
        }
        #pragma unroll
        for (int off = 32; off > 0; off >>= 1)
            #pragma unroll
            for (int h = 0; h < NH; ++h)
                mx[h] = fmaxf(mx[h], __shfl_xor(mx[h], off, 64));

        float pv[NH];
        #pragma unroll
        for (int h = 0; h < NH; ++h) {
            pv[h] = valid ? __expf(evv[h] - mx[h]) : 0.f;
            lv[h] = pv[h];
        }
        #pragma unroll
        for (int off = 32; off > 0; off >>= 1)
            #pragma unroll
            for (int h = 0; h < NH; ++h)
                lv[h] += __shfl_xor(lv[h], off, 64);

        // stash sorted (src, pv[]) — wave-private LDS, no barrier needed
        s_sh[w][lane] = mys;
        #pragma unroll
        for (int h = 0; h < NH; ++h) p_sh[w][lane][h] = pv[h];

        // ---- gather: 4 edges/iter; 16 lanes x 16 features per edge ----
        const int quarter = lane >> 4;
        const int l16 = lane & 15;
        const int f0 = l16 * 16;
        const int head = f0 / NF;        // NH=4: l16/4; NH=1: 0

        float acc[16];
        #pragma unroll
        for (int k = 0; k < 16; ++k) acc[k] = 0.f;

        const int iters = (deg + 3) >> 2;
        for (int t2 = 0; t2 < iters; ++t2) {
            int j = 4 * t2 + quarter;
            bool jv = j < deg;
            int jj = jv ? j : 0;
            int s = s_sh[w][jj];
            float p = jv ? p_sh[w][jj][head] : 0.f;
            const unsigned short* row = hp + (size_t)s * 256 + f0;
            half8 v0 = *(const half8*)(row);
            half8 v1 = *(const half8*)(row + 8);
            #pragma unroll
            for (int k = 0; k < 8; ++k) {
                acc[k]     = fmaf(p, (float)v0[k], acc[k]);
                acc[8 + k] = fmaf(p, (float)v1[k], acc[8 + k]);
            }
        }
        // reduce across the 4 edge-quarters (wave-uniform, all lanes active)
        #pragma unroll
        for (int k = 0; k < 16; ++k) {
            acc[k] += __shfl_xor(acc[k], 16, 64);
            acc[k] += __shfl_xor(acc[k], 32, 64);
        }
        if (lane < 16) {
            float li = 1.0f / (lv[head] + 1e-16f);
            float o[16];
            #pragma unroll
            for (int k = 0; k < 16; ++k) {
                o[k] = acc[k] * li;
                if (RELU) o[k] = fmaxf(o[k], 0.f);
            }
            if constexpr (F16OUT) {
                ushort8 u0, u1;
                #pragma unroll
                for (int k = 0; k < 8; ++k) {
                    u0[k] = f2h(o[k]);
                    u1[k] = f2h(o[8 + k]);
                }
                *(ushort8*)&outh[(size_t)node * 256 + f0]     = u0;
                *(ushort8*)&outh[(size_t)node * 256 + f0 + 8] = u1;
            } else {
                float* op = &out[(size_t)node * 256 + f0];
                *(float4*)&op[0]  = make_float4(o[0], o[1], o[2], o[3]);
                *(float4*)&op[4]  = make_float4(o[4], o[5], o[6], o[7]);
                *(float4*)&op[8]  = make_float4(o[8], o[9], o[10], o[11]);
                *(float4*)&op[12] = make_float4(o[12], o[13], o[14], o[15]);
            }
        }
    } else {
        // ---- deg > 64 deterministic ascending-src sweep (rare path) ----
        #pragma unroll
        for (int h = 0; h < NH; ++h) mx[h] = -INFINITY;
        for (int c = b + lane; c < e; c += 64) {
            int s = sorted[c];
            #pragma unroll
            for (int h = 0; h < NH; ++h) {
                float ev = ssrc[s * NH + h] + sv[h];
                ev = ev > 0.f ? ev : 0.2f * ev;
                mx[h] = fmaxf(mx[h], ev);   // max is order-invariant
            }
        }
        #pragma unroll
        for (int off = 32; off > 0; off >>= 1)
            #pragma unroll
            for (int h = 0; h < NH; ++h)
                mx[h] = fmaxf(mx[h], __shfl_xor(mx[h], off, 64));

        const int half = lane >> 5;
        const int l32 = lane & 31;
        const int f0 = l32 * 8;
        const int head = f0 / NF;

        float acc[8];
        #pragma unroll
        for (int k = 0; k < 8; ++k) acc[k] = 0.f;
        #pragma unroll
        for (int h = 0; h < NH; ++h) lv[h] = 0.f;

        int last = -1, round = 0;
        for (;;) {
            int myMin = 0x7FFFFFFF, myCnt = 0;
            for (int c = b + lane; c < e; c += 64) {
                int s = sorted[c];
                if (s > last) {
                    if (s < myMin) { myMin = s; myCnt = 1; }
                    else if (s == myMin) ++myCnt;
                }
            }
            #pragma unroll
            for (int off = 32; off > 0; off >>= 1) {
                int om = __shfl_xor(myMin, off, 64);
                int oc = __shfl_xor(myCnt, off, 64);
                if (om < myMin) { myMin = om; myCnt = oc; }
                else if (om == myMin) myCnt += oc;
            }
            if (myMin == 0x7FFFFFFF) break;     // wave-uniform exit
            const bool mine = ((round & 1) == half);
            float cf = (float)myCnt;
            float ph[NH];
            #pragma unroll
            for (int h = 0; h < NH; ++h) {
                float ev = ssrc[myMin * NH + h] + sv[h];
                ev = ev > 0.f ? ev : 0.2f * ev;
                ph[h] = __expf(ev - mx[h]);
            }
            if (mine && l32 == 0) {             // one lane per half owns lv
                #pragma unroll
                for (int h = 0; h < NH; ++h) lv[h] += cf * ph[h];
            }
            if (mine) {
                float p = cf * ph[head];
                half8 v = *(const half8*)(hp + (size_t)myMin * 256 + f0);
                #pragma unroll
                for (int k = 0; k < 8; ++k) acc[k] = fmaf(p, (float)v[k], acc[k]);
            }
            last = myMin; ++round;
        }
        #pragma unroll
        for (int off = 32; off > 0; off >>= 1)
            #pragma unroll
            for (int h = 0; h < NH; ++h)
                lv[h] += __shfl_xor(lv[h], off, 64);

        #pragma unroll
        for (int k = 0; k < 8; ++k) acc[k] += __shfl_xor(acc[k], 32, 64);

        if (lane < 32) {
            float li = 1.0f / (lv[head] + 1e-16f);
            float o[8];
            #pragma unroll
            for (int k = 0; k < 8; ++k) {
                o[k] = acc[k] * li;
                if (RELU) o[k] = fmaxf(o[k], 0.f);
            }
            if constexpr (F16OUT) {
                ushort8 u0;
                #pragma unroll
                for (int k = 0; k < 8; ++k) u0[k] = f2h(o[k]);
                *(ushort8*)&outh[(size_t)node * 256 + f0] = u0;
            } else {
                *(float4*)&out[(size_t)node * 256 + f0]     = make_float4(o[0], o[1], o[2], o[3]);
                *(float4*)&out[(size_t)node * 256 + f0 + 4] = make_float4(o[4], o[5], o[6], o[7]);
            }
        }
    }
}

// ---------------------------------------------------------------------------
extern "C" void kernel_launch(void* const* d_in, const int* in_sizes, int n_in,
                              void* d_out, int out_size, void* d_ws, size_t ws_size,
                              hipStream_t stream) {
    const float* x   = (const float*)d_in[0];
    const int*   ei  = (const int*)d_in[1];
    const float* W1  = (const float*)d_in[2];
    const float* a1s = (const float*)d_in[3];
    const float* a1d = (const float*)d_in[4];
    const float* W2  = (const float*)d_in[5];
    const float* a2s = (const float*)d_in[6];
    const float* a2d = (const float*)d_in[7];
    float* out = (float*)d_out;

    const int N = in_sizes[0] / 256;
    const int E = in_sizes[1] / 2;
    const int* src = ei;
    const int* dst = ei + E;

    // workspace carve-up
    unsigned short* hp = (unsigned short*)d_ws;     // N*256 fp16
    float* ssrc  = (float*)(hp + (size_t)N * 256);  // N*4
    float* sdst  = ssrc + (size_t)N * 4;            // N*4
    int*   deg   = (int*)(sdst + (size_t)N * 4);    // N
    int*   cur   = deg + N;                         // N
    int*   offs  = cur + N;                         // N+1
    int*   sorted= offs + N + 1;                    // E
    int*   bsums = sorted + E;                      // 64
    int*   boffs = bsums + 64;                      // 64 (unused, kept for layout)
    unsigned short* w1h = (unsigned short*)(boffs + 64);  // 65536 fp16
    unsigned short* w2h = w1h + 65536;                    // 65536 fp16

    // d_out doubles as fp16 scratch: hh (layer-1 output = layer-2 A) lives in
    // the first half; dead before the final aggregate overwrites d_out fp32.
    unsigned short* hh = (unsigned short*)d_out;    // N*256 fp16

    const int nb = (N + 1023) / 1024;
    const int prepblocks = ((N + 255) / 256) > 64 ? ((N + 255) / 256) : 64;

    // ---- prep: zero(deg) + W fp16 conversion ----
    prep<<<prepblocks, 256, 0, stream>>>(W1, W2, w1h, w2h, deg, N);

    // ---- CSR build ----
    hist_kernel<<<(E + 255) / 256, 256, 0, stream>>>(dst, deg, E);
    scan1<<<nb, 1024, 0, stream>>>(deg, offs, bsums, N);
    scan23<<<nb, 1024, 0, stream>>>(offs, cur, bsums, N, nb);
    scatter_kernel<<<(E + 255) / 256, 256, 0, stream>>>(src, dst, cur, sorted, E);

    int gemmblocks = (N + 127) / 128;
    int aggblocks = (N + 3) / 4;
    sort_csr<<<aggblocks, 256, 0, stream>>>(offs, sorted, N);

    // ---- layer 1 (gemm + fused scompute) ----
    gemm_sc<true, 4><<<gemmblocks, 512, 0, stream>>>(x, w1h, hp, a1s, a1d, ssrc, sdst, N);
    aggregate4<4, true, true><<<aggblocks, 256, 0, stream>>>(hp, ssrc, sdst, offs, sorted,
                                                             nullptr, hh, N);

    // ---- layer 2 (gemm + fused scompute) ----
    gemm_sc<false, 1><<<gemmblocks, 512, 0, stream>>>(hh, w2h, hp, a2s, a2d, ssrc, sdst, N);
    aggregate4<1, false, false><<<aggblocks, 256, 0, stream>>>(hp, ssrc, sdst, offs, sorted,
                                                               out, nullptr, N);
}